// Round 11
// baseline (4026.465 us; speedup 1.0000x reference)
//
#include <hip/hip_runtime.h>
#include <hip/hip_bf16.h>
#include <math.h>

using bf16 = __hip_bfloat16;

#define BB 1024
#define TT 13
#define YY 188
#define HH 512
#define GG 1536
#define YP 192
#define DS 13
#define NT 96    // GG/16 B-tiles along the gate dimension
#define NTO 12   // YP/16 B-tiles for the output projection

typedef __bf16 bf16x8 __attribute__((ext_vector_type(8)));
typedef float f32x4 __attribute__((ext_vector_type(4)));
typedef float f4 __attribute__((ext_vector_type(4)));

__device__ __forceinline__ float sigf(float x) { return 1.f / (1.f + expf(-x)); }
__device__ __forceinline__ bf16x8 ldf(const bf16* p) {
  return *reinterpret_cast<const bf16x8*>(p);
}
__device__ __forceinline__ f32x4 mf(bf16x8 a, bf16x8 b, f32x4 c) {
  return __builtin_amdgcn_mfma_f32_16x16x32_bf16(a, b, c, 0, 0, 0);
}
__device__ __forceinline__ void split2(float v, bf16& hi, bf16& lo) {
  hi = __float2bfloat16(v);
  lo = __float2bfloat16(v - __bfloat162float(hi));
}

// Per-phase cell table (single-layer dispatches), passed by value.
struct GruPhase {
  int ncells;
  int zmask;             // bit c: t==0 (skip gh GEMM, h_prev = 0)
  unsigned a1off[13];    // A1 element offset per cell
  unsigned hoff[13];     // h_prev element offset per cell
  unsigned ooff[13];     // h_out  element offset per cell
};

// Merged dual-layer cell table (<=25 cells: L0(s) + L1(s-1)), by value.
struct GruPhase2 {
  int ncells;
  unsigned zmask;        // bit c: t==0 cell
  unsigned laymask;      // bit c: cell is layer-1
  unsigned a1off[25];
  unsigned hoff[25];
  unsigned ooff[25];
};

// ---------------------------------------------------------------------------
// Swizzle a row-major (Nsrc x Ksrc) fp32 weight into KT-MAJOR MFMA B-frag
// order, split hi/lo, zero-padded. Tile (kt,nt) at elem (kt*ntiles + nt)*512;
// lane l holds W[nt*16+(l&15)][kt*32+(l>>4)*8+j], j=0..7 contiguous.
// ---------------------------------------------------------------------------
__global__ void k_swz2(const float* __restrict__ src, bf16* __restrict__ dhi,
                       bf16* __restrict__ dlo, int Nsrc, int Ksrc, int ntiles) {
  int idx = blockIdx.x * 256 + threadIdx.x;   // ((kt*ntiles+nt), lane)
  int l = idx & 63;
  int ktnt = idx >> 6;
  int nt = ktnt % ntiles, kt = ktnt / ntiles;
  int n = nt * 16 + (l & 15);
  int k0 = kt * 32 + (l >> 4) * 8;
#pragma unroll
  for (int j = 0; j < 8; ++j) {
    int k = k0 + j;
    float v = (n < Nsrc && k < Ksrc) ? src[(size_t)n * Ksrc + k] : 0.f;
    bf16 h, lo;
    split2(v, h, lo);
    dhi[(size_t)idx * 8 + j] = h;
    dlo[(size_t)idx * 8 + j] = lo;
  }
}

// Setup: 26-slot hi/lo token buffers (s<13: x[:,s,:]; s>=13: y_{s-13}), plus
// fp32 residual seeded with x[:,12,:].
__global__ void k_setup(const float* __restrict__ x, bf16* __restrict__ th,
                        bf16* __restrict__ tl, float* __restrict__ res) {
  int idx = blockIdx.x * 256 + threadIdx.x;
  const int total = 26 * BB * YP;
  if (idx < total) {
    int k = idx % YP;
    int b = (idx / YP) % BB;
    int s = idx / (YP * BB);
    float v = 0.f;
    if (s < TT && k < YY) v = x[((size_t)b * TT + s) * YY + k];
    bf16 h, lo;
    split2(v, h, lo);
    th[idx] = h; tl[idx] = lo;
  }
  if (idx < BB * YY) {
    int yy = idx % YY;
    int b = idx / YY;
    res[idx] = x[((size_t)b * TT + 12) * YY + yy];
  }
}

// ===========================================================================
// GRU_BODY: the proven v7 128x64 loop (R5/R6 verified: 136us @C=13; merged
// form R10-verified: 10.04us/cell). Expects in scope: tid,w,l,lr,lq,kq,rt,
// cw,m0, A1h,A1l,lda1r,KT1r, W1hp,W1lp,W2hp,W2lp,b1p,b2p, HPh,HPl,HOh,HOl,
// zero_h, Bl. Shared by gru2 (template) and gru2m (runtime select).
// ===========================================================================
#define GRU_BODY()                                                            \
  const int KT2 = zero_h ? 0 : 16;                                            \
  const f32x4 vzero = {0.f, 0.f, 0.f, 0.f};                                   \
  f32x4 arz[2][2][4];                                                         \
  f32x4 axn[2][4], ahn[2][4];                                                 \
  _Pragma("unroll")                                                           \
  for (int rf = 0; rf < 2; ++rf)                                              \
    _Pragma("unroll")                                                         \
    for (int ntl = 0; ntl < 4; ++ntl) {                                       \
      arz[rf][0][ntl] = vzero; arz[rf][1][ntl] = vzero;                       \
      axn[rf][ntl] = vzero; ahn[rf][ntl] = vzero;                             \
    }                                                                         \
  int tl2a[6], hlr[6];                                                        \
  size_t soff[6];                                                             \
  _Pragma("unroll")                                                           \
  for (int r = 0; r < 6; ++r) {                                               \
    const int tl2 = r * 4 + w;                                                \
    const int hl = tl2 & 1;                                                   \
    const int gn = tl2 >> 1;                                                  \
    const int g = gn >> 2, ntl = gn & 3;                                      \
    const int ntg = g * 32 + (cw >> 4) + ntl;                                 \
    tl2a[r] = tl2; hlr[r] = hl;                                               \
    soff[r] = ((size_t)ntg * 64 + l) * 8;                                     \
  }                                                                           \
  auto stage_load = [&](const bf16* Wh, const bf16* Wl2, int ktW,             \
                        bf16x8 (&v)[6]) {                                     \
    _Pragma("unroll")                                                         \
    for (int r = 0; r < 6; ++r)                                               \
      v[r] = ldf((hlr[r] ? Wl2 : Wh) + soff[r] + (size_t)ktW * (NT * 512));   \
  };                                                                          \
  auto stage_write = [&](bf16x8 (&v)[6], int buf) {                           \
    _Pragma("unroll")                                                         \
    for (int r = 0; r < 6; ++r)                                               \
      *(bf16x8*)(&Bl[buf][tl2a[r]][l * 8]) = v[r];                            \
  };                                                                          \
  auto aload = [&](const bf16* Ah, const bf16* Al, int lda, int ktA,          \
                   bf16x8 (&d)[2][2]) {                                       \
    _Pragma("unroll")                                                         \
    for (int rf = 0; rf < 2; ++rf) {                                          \
      const size_t ao = (size_t)(m0 + rf * 16 + lr) * lda + ktA * 32 + kq;    \
      d[rf][0] = ldf(Ah + ao);                                                \
      d[rf][1] = ldf(Al + ao);                                                \
    }                                                                         \
  };                                                                          \
  auto compute = [&](bf16x8 (&a)[2][2], int buf, f32x4 (&an)[2][4]) {         \
    _Pragma("unroll")                                                         \
    for (int g = 0; g < 3; ++g)                                               \
      _Pragma("unroll")                                                       \
      for (int ntl = 0; ntl < 4; ++ntl) {                                     \
        int tl2 = (g * 4 + ntl) * 2;                                          \
        bf16x8 bh  = *(const bf16x8*)(&Bl[buf][tl2][l * 8]);                  \
        bf16x8 blo = *(const bf16x8*)(&Bl[buf][tl2 + 1][l * 8]);              \
        _Pragma("unroll")                                                     \
        for (int rf = 0; rf < 2; ++rf) {                                      \
          if (g < 2)                                                          \
            arz[rf][g][ntl] = mf(a[rf][0], blo, mf(a[rf][1], bh,              \
                                 mf(a[rf][0], bh, arz[rf][g][ntl])));         \
          else                                                                \
            an[rf][ntl] = mf(a[rf][0], blo, mf(a[rf][1], bh,                  \
                             mf(a[rf][0], bh, an[rf][ntl])));                 \
        }                                                                     \
      }                                                                       \
  };                                                                          \
  auto acopy = [&](bf16x8 (&dst)[2][2], bf16x8 (&src)[2][2]) {                \
    _Pragma("unroll")                                                         \
    for (int rf = 0; rf < 2; ++rf) {                                          \
      dst[rf][0] = src[rf][0];                                                \
      dst[rf][1] = src[rf][1];                                                \
    }                                                                         \
  };                                                                          \
  bf16x8 w0[6], w1[6], acur[2][2], anx[2][2];                                 \
  stage_load(W1hp, W1lp, 0, w0);                                              \
  aload(A1h, A1l, lda1r, 0, acur);                                            \
  stage_write(w0, 0);                                                         \
  __syncthreads();                                                            \
  for (int kt = 0; kt < KT1r; ++kt) {                                         \
    const int buf = kt & 1;                                                   \
    const bool more1 = (kt + 1 < KT1r);                                       \
    const bool next = more1 || (KT2 > 0);                                     \
    if (more1)      { stage_load(W1hp, W1lp, kt + 1, w1); aload(A1h, A1l, lda1r, kt + 1, anx); } \
    else if (KT2)   { stage_load(W2hp, W2lp, 0, w1);      aload(HPh, HPl, HH, 0, anx); }         \
    compute(acur, buf, axn);                                                  \
    if (next) stage_write(w1, buf ^ 1);                                       \
    __syncthreads();                                                          \
    if (next) acopy(acur, anx);                                               \
  }                                                                           \
  if (KT2) {                                                                  \
    for (int kt = 0; kt < 16; ++kt) {                                         \
      const int buf = (KT1r + kt) & 1;                                        \
      const bool next = (kt + 1 < 16);                                        \
      if (next) { stage_load(W2hp, W2lp, kt + 1, w1); aload(HPh, HPl, HH, kt + 1, anx); } \
      compute(acur, buf, ahn);                                                \
      if (next) stage_write(w1, buf ^ 1);                                     \
      __syncthreads();                                                        \
      if (next) acopy(acur, anx);                                             \
    }                                                                         \
  }                                                                           \
  _Pragma("unroll")                                                           \
  for (int ntl = 0; ntl < 4; ++ntl) {                                         \
    const int col = cw + ntl * 16 + lr;                                       \
    const float bx0 = b1p[col], bx1 = b1p[col + HH], bx2 = b1p[col + 2 * HH]; \
    const float bh0 = b2p[col], bh1 = b2p[col + HH], bh2 = b2p[col + 2 * HH]; \
    _Pragma("unroll")                                                         \
    for (int rf = 0; rf < 2; ++rf)                                            \
      _Pragma("unroll")                                                       \
      for (int i = 0; i < 4; ++i) {                                           \
        const int row = m0 + rf * 16 + lq * 4 + i;                            \
        const float rr = sigf(arz[rf][0][ntl][i] + bx0 + bh0);                \
        const float zz = sigf(arz[rf][1][ntl][i] + bx1 + bh1);                \
        const float nn = tanhf(axn[rf][ntl][i] + bx2 + rr * (ahn[rf][ntl][i] + bh2)); \
        float hp = 0.f;                                                       \
        const size_t hidx = (size_t)row * HH + col;                           \
        if (!zero_h)                                                          \
          hp = __bfloat162float(HPh[hidx]) + __bfloat162float(HPl[hidx]);     \
        const float hn = (1.f - zz) * nn + zz * hp;                           \
        bf16 sh, sl;                                                          \
        split2(hn, sh, sl);                                                   \
        HOh[hidx] = sh;                                                       \
        HOl[hidx] = sl;                                                       \
      }                                                                       \
  }

// ---------------------------------------------------------------------------
// gru2: v7 single-layer kernel, R6 grid orientation (x=colgroup -> XCD-local
// W in L2; validated 136us config). Used in the decode tail + SKEW2 path.
// ---------------------------------------------------------------------------
template <int KT1>
__global__ __launch_bounds__(256, 2) void gru2(
    const bf16* __restrict__ a1h, const bf16* __restrict__ a1l, int lda1,
    const bf16* __restrict__ W1h, const bf16* __restrict__ W1l,
    const float* __restrict__ b1,
    const bf16* __restrict__ hbh, const bf16* __restrict__ hbl,
    const bf16* __restrict__ W2h, const bf16* __restrict__ W2l,
    const float* __restrict__ b2,
    bf16* __restrict__ obh, bf16* __restrict__ obl,
    GruPhase ph)
{
  __shared__ __align__(16) __bf16 Bl[2][24][512];
  const int tid = threadIdx.x;
  const int w = tid >> 6, l = tid & 63;
  const int lr = l & 15, lq = l >> 4, kq = lq * 8;
  const int cell = blockIdx.y >> 3, rt = blockIdx.y & 7;
  const int cw = blockIdx.x * 64;
  const int m0 = rt * 128 + w * 32;
  const bf16* A1h = a1h + ph.a1off[cell];
  const bf16* A1l = a1l + ph.a1off[cell];
  const bf16* HPh = hbh + ph.hoff[cell];
  const bf16* HPl = hbl + ph.hoff[cell];
  bf16* HOh = obh + ph.ooff[cell];
  bf16* HOl = obl + ph.ooff[cell];
  const int zero_h = (ph.zmask >> cell) & 1;
  const int KT1r = KT1;
  const int lda1r = lda1;
  const bf16 *W1hp = W1h, *W1lp = W1l, *W2hp = W2h, *W2lp = W2l;
  const float *b1p = b1, *b2p = b2;
  GRU_BODY()
}

// ---------------------------------------------------------------------------
// gru2m: MERGED dual-layer dispatch, D(s) = L0(s) u L1(s-1). Legal for ALL
// s<=12: L0(s) reads x-tokens (slot s<13) + h0 parity (s-1)&1; L1(s-1)
// reads L0(s-1) output + h1 parity (s-2)&1; L0(s) writes h0 parity s&1 --
// disjoint from L1(s-1)'s h0 reads. R10-verified at 10.04us/cell.
// ---------------------------------------------------------------------------
__global__ __launch_bounds__(256, 2) void gru2m(
    const bf16* __restrict__ tokh, const bf16* __restrict__ tokl,
    bf16* __restrict__ h0h, bf16* __restrict__ h0l,
    bf16* __restrict__ h1h, bf16* __restrict__ h1l,
    const bf16* __restrict__ W0h, const bf16* __restrict__ W0l,
    const bf16* __restrict__ Wh0h, const bf16* __restrict__ Wh0l,
    const float* __restrict__ bi0, const float* __restrict__ bh0,
    const bf16* __restrict__ Wi1h, const bf16* __restrict__ Wi1l,
    const bf16* __restrict__ Wh1h, const bf16* __restrict__ Wh1l,
    const float* __restrict__ bi1, const float* __restrict__ bh1,
    GruPhase2 ph)
{
  __shared__ __align__(16) __bf16 Bl[2][24][512];
  const int tid = threadIdx.x;
  const int w = tid >> 6, l = tid & 63;
  const int lr = l & 15, lq = l >> 4, kq = lq * 8;
  const int cell = blockIdx.y >> 3, rt = blockIdx.y & 7;
  const int cw = blockIdx.x * 64;
  const int m0 = rt * 128 + w * 32;
  const int isL1 = (ph.laymask >> cell) & 1;
  const int KT1r = isL1 ? (HH / 32) : (YP / 32);
  const int lda1r = isL1 ? HH : YP;
  const bf16* A1h = (isL1 ? h0h : tokh) + ph.a1off[cell];
  const bf16* A1l = (isL1 ? h0l : tokl) + ph.a1off[cell];
  const bf16* HPh = (isL1 ? h1h : h0h) + ph.hoff[cell];
  const bf16* HPl = (isL1 ? h1l : h0l) + ph.hoff[cell];
  bf16* HOh = (isL1 ? h1h : h0h) + ph.ooff[cell];
  bf16* HOl = (isL1 ? h1l : h0l) + ph.ooff[cell];
  const bf16* W1hp = isL1 ? Wi1h : W0h;
  const bf16* W1lp = isL1 ? Wi1l : W0l;
  const bf16* W2hp = isL1 ? Wh1h : Wh0h;
  const bf16* W2lp = isL1 ? Wh1l : Wh0l;
  const float* b1p = isL1 ? bi1 : bi0;
  const float* b2p = isL1 ? bh1 : bh0;
  const int zero_h = (ph.zmask >> cell) & 1;
  GRU_BODY()
}

// ---------------------------------------------------------------------------
// gru2n (small-C path): proven R1/v3 128x32 kernel, R6 orientation.
// Higher occupancy fills the chip at small C (decode tail).
// ---------------------------------------------------------------------------
template <int KT1>
__global__ __launch_bounds__(256) void gru2n(
    const bf16* __restrict__ a1h, const bf16* __restrict__ a1l, int lda1,
    const bf16* __restrict__ W1h, const bf16* __restrict__ W1l,
    const float* __restrict__ b1,
    const bf16* __restrict__ hbh, const bf16* __restrict__ hbl,
    const bf16* __restrict__ W2h, const bf16* __restrict__ W2l,
    const float* __restrict__ b2,
    bf16* __restrict__ obh, bf16* __restrict__ obl,
    GruPhase ph)
{
  __shared__ __align__(16) __bf16 Bl[2][12][512];
  const int tid = threadIdx.x;
  const int w = tid >> 6, l = tid & 63;
  const int lr = l & 15, lq = l >> 4, kq = lq * 8;
  const int cell = blockIdx.y >> 3, rt = blockIdx.y & 7;
  const int cw = blockIdx.x * 32;
  const int m0 = rt * 128 + w * 32;
  const bf16* A1h = a1h + ph.a1off[cell];
  const bf16* A1l = a1l + ph.a1off[cell];
  const bf16* HPh = hbh + ph.hoff[cell];
  const bf16* HPl = hbl + ph.hoff[cell];
  bf16* HOh = obh + ph.ooff[cell];
  bf16* HOl = obl + ph.ooff[cell];
  const int zero_h = (ph.zmask >> cell) & 1;
  const int KT2 = zero_h ? 0 : 16;

  const f32x4 vzero = {0.f, 0.f, 0.f, 0.f};
  f32x4 arz[2][2][2];
  f32x4 axn[2][2], ahn[2][2];
#pragma unroll
  for (int rf = 0; rf < 2; ++rf)
#pragma unroll
    for (int ntl = 0; ntl < 2; ++ntl) {
      arz[rf][0][ntl] = vzero; arz[rf][1][ntl] = vzero;
      axn[rf][ntl] = vzero; ahn[rf][ntl] = vzero;
    }

  int tl2a[3], uia[3], hlr[3];
  size_t soff[3];
#pragma unroll
  for (int r = 0; r < 3; ++r) {
    int u = r * 256 + tid;
    int tl2 = u >> 6;
    int ui = u & 63;
    int hl = tl2 & 1;
    int gn = tl2 >> 1;
    int g = gn >> 1, ntl = gn & 1;
    int ntg = g * 32 + (cw >> 4) + ntl;
    tl2a[r] = tl2; uia[r] = ui; hlr[r] = hl;
    soff[r] = ((size_t)ntg * 64 + ui) * 8;
  }

  auto stage_load = [&](const bf16* Wh, const bf16* Wl2, int ktW,
                        bf16x8 (&v)[3]) {
#pragma unroll
    for (int r = 0; r < 3; ++r)
      v[r] = ldf((hlr[r] ? Wl2 : Wh) + soff[r] + (size_t)ktW * (NT * 512));
  };
  auto stage_write = [&](bf16x8 (&v)[3], int buf) {
#pragma unroll
    for (int r = 0; r < 3; ++r)
      *(bf16x8*)(&Bl[buf][tl2a[r]][uia[r] * 8]) = v[r];
  };
  auto aload = [&](const bf16* Ah, const bf16* Al, int lda, int ktA,
                   bf16x8 (&d)[2][2]) {
#pragma unroll
    for (int rf = 0; rf < 2; ++rf) {
      const size_t ao = (size_t)(m0 + rf * 16 + lr) * lda + ktA * 32 + kq;
      d[rf][0] = ldf(Ah + ao);
      d[rf][1] = ldf(Al + ao);
    }
  };
  auto compute = [&](bf16x8 (&a)[2][2], int buf, f32x4 (&an)[2][2]) {
#pragma unroll
    for (int g = 0; g < 3; ++g)
#pragma unroll
      for (int ntl = 0; ntl < 2; ++ntl) {
        int tl2 = (g * 2 + ntl) * 2;
        bf16x8 bh  = *(const bf16x8*)(&Bl[buf][tl2][l * 8]);
        bf16x8 blo = *(const bf16x8*)(&Bl[buf][tl2 + 1][l * 8]);
#pragma unroll
        for (int rf = 0; rf < 2; ++rf) {
          if (g < 2)
            arz[rf][g][ntl] = mf(a[rf][0], blo, mf(a[rf][1], bh,
                                 mf(a[rf][0], bh, arz[rf][g][ntl])));
          else
            an[rf][ntl] = mf(a[rf][0], blo, mf(a[rf][1], bh,
                             mf(a[rf][0], bh, an[rf][ntl])));
        }
      }
  };
  auto acopy = [&](bf16x8 (&dst)[2][2], bf16x8 (&src)[2][2]) {
#pragma unroll
    for (int rf = 0; rf < 2; ++rf) {
      dst[rf][0] = src[rf][0];
      dst[rf][1] = src[rf][1];
    }
  };

  bf16x8 w0[3], w1[3], acur[2][2], anx[2][2];

  stage_load(W1h, W1l, 0, w0);
  aload(A1h, A1l, lda1, 0, acur);
  stage_write(w0, 0);
  __syncthreads();

  for (int kt = 0; kt < KT1; ++kt) {
    const int buf = kt & 1;
    const bool more1 = (kt + 1 < KT1);
    const bool next = more1 || (KT2 > 0);
    if (more1)      { stage_load(W1h, W1l, kt + 1, w1); aload(A1h, A1l, lda1, kt + 1, anx); }
    else if (KT2)   { stage_load(W2h, W2l, 0, w1);      aload(HPh, HPl, HH, 0, anx); }
    compute(acur, buf, axn);
    if (next) stage_write(w1, buf ^ 1);
    __syncthreads();
    if (next) acopy(acur, anx);
  }
  if (KT2) {
    for (int kt = 0; kt < 16; ++kt) {
      const int buf = (KT1 + kt) & 1;
      const bool next = (kt + 1 < 16);
      if (next) { stage_load(W2h, W2l, kt + 1, w1); aload(HPh, HPl, HH, kt + 1, anx); }
      compute(acur, buf, ahn);
      if (next) stage_write(w1, buf ^ 1);
      __syncthreads();
      if (next) acopy(acur, anx);
    }
  }

#pragma unroll
  for (int ntl = 0; ntl < 2; ++ntl) {
    const int col = cw + ntl * 16 + lr;
    const float bx0 = b1[col], bx1 = b1[col + HH], bx2 = b1[col + 2 * HH];
    const float bh0 = b2[col], bh1 = b2[col + HH], bh2 = b2[col + 2 * HH];
#pragma unroll
    for (int rf = 0; rf < 2; ++rf)
#pragma unroll
      for (int i = 0; i < 4; ++i) {
        const int row = m0 + rf * 16 + lq * 4 + i;
        const float rr = sigf(arz[rf][0][ntl][i] + bx0 + bh0);
        const float zz = sigf(arz[rf][1][ntl][i] + bx1 + bh1);
        const float nn = tanhf(axn[rf][ntl][i] + bx2 + rr * (ahn[rf][ntl][i] + bh2));
        float hp = 0.f;
        const size_t hidx = (size_t)row * HH + col;
        if (!zero_h)
          hp = __bfloat162float(HPh[hidx]) + __bfloat162float(HPl[hidx]);
        const float hn = (1.f - zz) * nn + zz * hp;
        bf16 sh, sl;
        split2(hn, sh, sl);
        HOh[hidx] = sh;
        HOl[hidx] = sl;
      }
  }
}

// ---------------------------------------------------------------------------
// Output projection (MFMA): o = relu(h1) @ W_out^T + b_out + res.
// grid(6, 8) = 48 blocks (32-col tiles); math identical to R6 version.
// ---------------------------------------------------------------------------
__global__ __launch_bounds__(256) void out_m(
    const bf16* __restrict__ h1h, const bf16* __restrict__ h1l,
    const bf16* __restrict__ Wh, const bf16* __restrict__ Wl,
    const float* __restrict__ bo,
    float* __restrict__ res,
    bf16* __restrict__ yh, bf16* __restrict__ yl,
    float* __restrict__ outp, int d)
{
  const int tid = threadIdx.x;
  const int w = tid >> 6, l = tid & 63;
  const int lr = l & 15, lq = l >> 4, kq = lq * 8;
  const int m0 = blockIdx.y * 128 + w * 32;
  const int cw = blockIdx.x * 32;

  const f32x4 vzero = {0.f, 0.f, 0.f, 0.f};
  f32x4 acc[2][2];
#pragma unroll
  for (int rf = 0; rf < 2; ++rf)
#pragma unroll
    for (int ntl = 0; ntl < 2; ++ntl) acc[rf][ntl] = vzero;

  for (int kt = 0; kt < HH / 32; ++kt) {
    bf16x8 ah[2], al[2];
#pragma unroll
    for (int rf = 0; rf < 2; ++rf) {
      const size_t ao = (size_t)(m0 + rf * 16 + lr) * HH + kt * 32 + kq;
      bf16x8 hh = ldf(h1h + ao);
      bf16x8 hl = ldf(h1l + ao);
#pragma unroll
      for (int j = 0; j < 8; ++j) {
        float v = fmaxf((float)hh[j] + (float)hl[j], 0.f);
        __bf16 vh = (__bf16)v;
        __bf16 vl = (__bf16)(v - (float)vh);
        ah[rf][j] = vh;
        al[rf][j] = vl;
      }
    }
#pragma unroll
    for (int ntl = 0; ntl < 2; ++ntl) {
      const int nt = (cw >> 4) + ntl;
      const size_t bo_ = ((size_t)(kt * NTO + nt) * 64 + l) * 8;
      bf16x8 bh = ldf(Wh + bo_);
      bf16x8 bl = ldf(Wl + bo_);
#pragma unroll
      for (int rf = 0; rf < 2; ++rf)
        acc[rf][ntl] = mf(ah[rf], bl, mf(al[rf], bh,
                          mf(ah[rf], bh, acc[rf][ntl])));
    }
  }

#pragma unroll
  for (int ntl = 0; ntl < 2; ++ntl) {
    const int col = cw + ntl * 16 + lr;
    if (col >= YY) continue;           // padded cols 188..191: no writes
    const float bc = bo[col];
#pragma unroll
    for (int rf = 0; rf < 2; ++rf)
#pragma unroll
      for (int i = 0; i < 4; ++i) {
        const int row = m0 + rf * 16 + lq * 4 + i;
        const int ridx = row * YY + col;
        float o = acc[rf][ntl][i] + bc + res[ridx];
        res[ridx] = o;
        outp[((size_t)row * DS + d) * YY + col] = o;
        bf16 sh, sl;
        split2(o, sh, sl);
        yh[(size_t)row * YP + col] = sh;
        yl[(size_t)row * YP + col] = sl;
      }
  }
}

extern "C" void kernel_launch(void* const* d_in, const int* in_sizes, int n_in,
                              void* d_out, int out_size, void* d_ws, size_t ws_size,
                              hipStream_t stream)
{
  // role mapping insurance (dict-order signature, greedy fallback)
  static const int sig_dict[11] = {2501632, 288768, 786432, 1536, 1536,
                                   786432, 786432, 1536, 1536, 96256, 188};
  int map[11];
  bool dict_ok = (n_in == 11);
  if (dict_ok)
    for (int r = 0; r < 11; ++r)
      if (in_sizes[r] != sig_dict[r]) { dict_ok = false; break; }
  if (dict_ok) { for (int r = 0; r < 11; ++r) map[r] = r; }
  else {
    bool used[16] = {};
    for (int r = 0; r < 11; ++r) {
      map[r] = r < n_in ? r : 0;
      for (int i = 0; i < n_in && i < 16; ++i)
        if (!used[i] && in_sizes[i] == sig_dict[r]) { map[r] = i; used[i] = true; break; }
    }
  }
  const float* x     = (const float*)d_in[map[0]];
  const float* W_ih0 = (const float*)d_in[map[1]];
  const float* W_hh0 = (const float*)d_in[map[2]];
  const float* b_ih0 = (const float*)d_in[map[3]];
  const float* b_hh0 = (const float*)d_in[map[4]];
  const float* W_ih1 = (const float*)d_in[map[5]];
  const float* W_hh1 = (const float*)d_in[map[6]];
  const float* b_ih1 = (const float*)d_in[map[7]];
  const float* b_hh1 = (const float*)d_in[map[8]];
  const float* W_out = (const float*)d_in[map[9]];
  const float* b_out = (const float*)d_in[map[10]];
  float* outp = (float*)d_out;

  const int S    = (ws_size >= (size_t)160 << 20) ? 13 : 7;
  const int SKEW = (S == 13) ? 1 : 2;
  const int NPH  = 12 * SKEW + 13;

  char* p = (char*)d_ws;
  auto alloc = [&](size_t bytes) { char* q = p; p += (bytes + 255) & ~(size_t)255; return q; };
  bf16* tokh = (bf16*)alloc((size_t)26 * BB * YP * 2);
  bf16* tokl = (bf16*)alloc((size_t)26 * BB * YP * 2);
  bf16* W0h  = (bf16*)alloc((size_t)GG * YP * 2);
  bf16* W0l  = (bf16*)alloc((size_t)GG * YP * 2);
  bf16* Wh0h = (bf16*)alloc((size_t)GG * HH * 2);
  bf16* Wh0l = (bf16*)alloc((size_t)GG * HH * 2);
  bf16* Wi1h = (bf16*)alloc((size_t)GG * HH * 2);
  bf16* Wi1l = (bf16*)alloc((size_t)GG * HH * 2);
  bf16* Wh1h = (bf16*)alloc((size_t)GG * HH * 2);
  bf16* Wh1l = (bf16*)alloc((size_t)GG * HH * 2);
  bf16* Woh  = (bf16*)alloc((size_t)YP * HH * 2);   // swizzled W_out frags
  bf16* Wol  = (bf16*)alloc((size_t)YP * HH * 2);
  bf16* h0h = (bf16*)alloc((size_t)2 * S * BB * HH * 2);  // parity x slot
  bf16* h0l = (bf16*)alloc((size_t)2 * S * BB * HH * 2);
  bf16* h1h = (bf16*)alloc((size_t)2 * S * BB * HH * 2);
  bf16* h1l = (bf16*)alloc((size_t)2 * S * BB * HH * 2);
  float* res = (float*)alloc((size_t)BB * YY * 4);

  k_setup<<<(26 * BB * YP + 255) / 256, 256, 0, stream>>>(x, tokh, tokl, res);
  k_swz2<<<NT * (YP / 32) * 64 / 256, 256, 0, stream>>>(W_ih0, W0h, W0l, GG, YY, NT);
  k_swz2<<<NT * (HH / 32) * 64 / 256, 256, 0, stream>>>(W_hh0, Wh0h, Wh0l, GG, HH, NT);
  k_swz2<<<NT * (HH / 32) * 64 / 256, 256, 0, stream>>>(W_ih1, Wi1h, Wi1l, GG, HH, NT);
  k_swz2<<<NT * (HH / 32) * 64 / 256, 256, 0, stream>>>(W_hh1, Wh1h, Wh1l, GG, HH, NT);
  k_swz2<<<NTO * (HH / 32) * 64 / 256, 256, 0, stream>>>(W_out, Woh, Wol, YY, HH, NTO);

  // phase cell-table builder (single-layer structs, SKEW-general)
  auto buildPhase = [&](int phs, GruPhase& P0, GruPhase& P1) {
    P0 = GruPhase{}; P1 = GruPhase{};
    const int pprev = (phs + 1) & 1, pcur = phs & 1;
    int C = 0;
    for (int d = 0; d < DS; ++d) {
      int t = phs - SKEW * d;
      if (t < 0 || t > 12) continue;
      int c = C++;
      P0.a1off[c] = (unsigned)((d + t) * BB * YP);
      P0.hoff[c]  = (unsigned)((pprev * S + d % S) * BB * HH);
      P0.ooff[c]  = (unsigned)((pcur * S + d % S) * BB * HH);
      if (t == 0) P0.zmask |= 1 << c;
      P1.a1off[c] = P0.ooff[c];
      P1.hoff[c]  = P0.hoff[c];
      P1.ooff[c]  = P0.ooff[c];
    }
    P0.ncells = P1.ncells = C;
    P1.zmask = P0.zmask;
    return C;
  };
  auto launchL0 = [&](const GruPhase& P0, int C) {
    if (C <= 5) {
      gru2n<YP / 32><<<dim3(16, C * 8), 256, 0, stream>>>(
          tokh, tokl, YP, W0h, W0l, b_ih0, h0h, h0l, Wh0h, Wh0l, b_hh0,
          h0h, h0l, P0);
    } else {
      gru2<YP / 32><<<dim3(8, C * 8), 256, 0, stream>>>(
          tokh, tokl, YP, W0h, W0l, b_ih0, h0h, h0l, Wh0h, Wh0l, b_hh0,
          h0h, h0l, P0);
    }
  };
  auto launchL1 = [&](const GruPhase& P1, int C) {
    if (C <= 5) {
      gru2n<HH / 32><<<dim3(16, C * 8), 256, 0, stream>>>(
          h0h, h0l, HH, Wi1h, Wi1l, b_ih1, h1h, h1l, Wh1h, Wh1l, b_hh1,
          h1h, h1l, P1);
    } else {
      gru2<HH / 32><<<dim3(8, C * 8), 256, 0, stream>>>(
          h0h, h0l, HH, Wi1h, Wi1l, b_ih1, h1h, h1l, Wh1h, Wh1l, b_hh1,
          h1h, h1l, P1);
    }
  };
  auto launchOut = [&](int d) {
    const int pph = 12 + SKEW * d;
    const size_t hoff = (size_t)((pph & 1) * S + d % S) * BB * HH;
    out_m<<<dim3(6, 8), 256, 0, stream>>>(
        h1h + hoff, h1l + hoff, Woh, Wol, b_out, res,
        tokh + (size_t)(13 + d) * BB * YP, tokl + (size_t)(13 + d) * BB * YP,
        outp, d);
  };

  if (SKEW == 1) {
    // ---- merged wavefront D(s) = L0(s) + L1(s-1), s=0..12 (R11: extended
    // to the full ramp; cell construction degenerates correctly at s=0).
    for (int s = 0; s <= 12; ++s) {
      GruPhase2 M{};
      int c = 0;
      {  // L0 cells of phase s
        const int pprev = (s + 1) & 1, pcur = s & 1;
        for (int d = 0; d < DS; ++d) {
          int t = s - d;
          if (t < 0 || t > 12) continue;
          M.a1off[c] = (unsigned)((d + t) * BB * YP);
          M.hoff[c]  = (unsigned)((pprev * S + d % S) * BB * HH);
          M.ooff[c]  = (unsigned)((pcur * S + d % S) * BB * HH);
          if (t == 0) M.zmask |= 1u << c;
          ++c;
        }
      }
      {  // L1 cells of phase s-1 (empty at s=0)
        const int pp = s - 1;
        const int pprev = (pp + 1) & 1, pcur = pp & 1;
        for (int d = 0; d < DS; ++d) {
          int t = pp - d;
          if (t < 0 || t > 12) continue;
          M.laymask |= 1u << c;
          M.a1off[c] = (unsigned)((pcur * S + d % S) * BB * HH);  // L0(pp) out
          M.hoff[c]  = (unsigned)((pprev * S + d % S) * BB * HH);
          M.ooff[c]  = (unsigned)((pcur * S + d % S) * BB * HH);
          if (t == 0) M.zmask |= 1u << c;
          ++c;
        }
      }
      M.ncells = c;
      gru2m<<<dim3(8, c * 8), 256, 0, stream>>>(
          tokh, tokl, h0h, h0l, h1h, h1l,
          W0h, W0l, Wh0h, Wh0l, b_ih0, b_hh0,
          Wi1h, Wi1l, Wh1h, Wh1l, b_ih1, b_hh1, M);
    }
    // ---- L1(12) standalone (C=13)
    {
      GruPhase P0, P1;
      int C = buildPhase(12, P0, P1);
      launchL1(P1, C);
    }
    // ---- decode: serial chain out_m(d) -> L0(13+d) -> L1(13+d)
    for (int d = 0; d <= 12; ++d) {
      launchOut(d);
      if (d < 12) {
        GruPhase P0, P1;
        int C = buildPhase(13 + d, P0, P1);
        launchL0(P0, C);
        launchL1(P1, C);
      }
    }
  } else {
    // SKEW=2 fallback: proven R6-style schedule (no merge)
    for (int phs = 0; phs < NPH; ++phs) {
      GruPhase P0, P1;
      int C = buildPhase(phs, P0, P1);
      launchL0(P0, C);
      launchL1(P1, C);
      if (phs >= 12 && (phs - 12) % SKEW == 0) launchOut((phs - 12) / SKEW);
    }
  }
}

// Round 12
// 3882.911 us; speedup vs baseline: 1.0370x; 1.0370x over previous
//
#include <hip/hip_runtime.h>
#include <hip/hip_bf16.h>
#include <math.h>

using bf16 = __hip_bfloat16;

#define BB 1024
#define TT 13
#define YY 188
#define HH 512
#define GG 1536
#define YP 192
#define DS 13
#define NT 96    // GG/16 B-tiles along the gate dimension
#define NTO 12   // YP/16 B-tiles for the output projection

typedef __bf16 bf16x8 __attribute__((ext_vector_type(8)));
typedef _Float16 f16x8 __attribute__((ext_vector_type(8)));
typedef float f32x4 __attribute__((ext_vector_type(4)));
typedef float f4 __attribute__((ext_vector_type(4)));

__device__ __forceinline__ float sigf(float x) { return 1.f / (1.f + expf(-x)); }
__device__ __forceinline__ bf16x8 ldf(const bf16* p) {
  return *reinterpret_cast<const bf16x8*>(p);
}
__device__ __forceinline__ f16x8 ldh(const _Float16* p) {
  return *reinterpret_cast<const f16x8*>(p);
}
__device__ __forceinline__ f32x4 mf(bf16x8 a, bf16x8 b, f32x4 c) {
  return __builtin_amdgcn_mfma_f32_16x16x32_bf16(a, b, c, 0, 0, 0);
}
__device__ __forceinline__ f32x4 mh(f16x8 a, f16x8 b, f32x4 c) {
  return __builtin_amdgcn_mfma_f32_16x16x32_f16(a, b, c, 0, 0, 0);
}
__device__ __forceinline__ void split2(float v, bf16& hi, bf16& lo) {
  hi = __float2bfloat16(v);
  lo = __float2bfloat16(v - __bfloat162float(hi));
}
__device__ __forceinline__ void split2h(float v, _Float16& hi, _Float16& lo) {
  hi = (_Float16)v;
  lo = (_Float16)(v - (float)hi);
}

// Per-phase cell table (single-layer dispatches), passed by value.
struct GruPhase {
  int ncells;
  int zmask;             // bit c: t==0 (skip gh GEMM, h_prev = 0)
  unsigned a1off[13];    // A1 element offset per cell
  unsigned hoff[13];     // h_prev element offset per cell
  unsigned ooff[13];     // h_out  element offset per cell
};

// Merged dual-layer cell table (<=25 cells: L0(s) + L1(s-1)), by value.
struct GruPhase2 {
  int ncells;
  unsigned zmask;        // bit c: t==0 cell
  unsigned laymask;      // bit c: cell is layer-1
  unsigned a1off[25];
  unsigned hoff[25];
  unsigned ooff[25];
};

// ---------------------------------------------------------------------------
// k_swzh: swizzle a row-major (Nsrc x Ksrc) fp32 weight into KT-MAJOR MFMA
// B-frag order as SINGLE fp16 (R12: W precision 2^-11 rel; the 2-term
// fp16 scheme keeps A at 2^-22 via hi/lo). Tile (kt,nt) at elem
// (kt*ntiles+nt)*512; lane l holds W[nt*16+(l&15)][kt*32+(l>>4)*8+j].
// ---------------------------------------------------------------------------
__global__ void k_swzh(const float* __restrict__ src, _Float16* __restrict__ dh,
                       int Nsrc, int Ksrc, int ntiles) {
  int idx = blockIdx.x * 256 + threadIdx.x;   // ((kt*ntiles+nt), lane)
  int l = idx & 63;
  int ktnt = idx >> 6;
  int nt = ktnt % ntiles, kt = ktnt / ntiles;
  int n = nt * 16 + (l & 15);
  int k0 = kt * 32 + (l >> 4) * 8;
#pragma unroll
  for (int j = 0; j < 8; ++j) {
    int k = k0 + j;
    float v = (n < Nsrc && k < Ksrc) ? src[(size_t)n * Ksrc + k] : 0.f;
    dh[(size_t)idx * 8 + j] = (_Float16)v;
  }
}

// k_swz2: bf16 hi/lo swizzle -- retained for W_out (out_m keeps 3-term bf16).
__global__ void k_swz2(const float* __restrict__ src, bf16* __restrict__ dhi,
                       bf16* __restrict__ dlo, int Nsrc, int Ksrc, int ntiles) {
  int idx = blockIdx.x * 256 + threadIdx.x;
  int l = idx & 63;
  int ktnt = idx >> 6;
  int nt = ktnt % ntiles, kt = ktnt / ntiles;
  int n = nt * 16 + (l & 15);
  int k0 = kt * 32 + (l >> 4) * 8;
#pragma unroll
  for (int j = 0; j < 8; ++j) {
    int k = k0 + j;
    float v = (n < Nsrc && k < Ksrc) ? src[(size_t)n * Ksrc + k] : 0.f;
    bf16 h, lo;
    split2(v, h, lo);
    dhi[(size_t)idx * 8 + j] = h;
    dlo[(size_t)idx * 8 + j] = lo;
  }
}

// Setup: 26-slot hi/lo fp16 token buffers, fp32 residual from x[:,12,:].
__global__ void k_setup(const float* __restrict__ x, _Float16* __restrict__ th,
                        _Float16* __restrict__ tl, float* __restrict__ res) {
  int idx = blockIdx.x * 256 + threadIdx.x;
  const int total = 26 * BB * YP;
  if (idx < total) {
    int k = idx % YP;
    int b = (idx / YP) % BB;
    int s = idx / (YP * BB);
    float v = 0.f;
    if (s < TT && k < YY) v = x[((size_t)b * TT + s) * YY + k];
    _Float16 h, lo;
    split2h(v, h, lo);
    th[idx] = h; tl[idx] = lo;
  }
  if (idx < BB * YY) {
    int yy = idx % YY;
    int b = idx / YY;
    res[idx] = x[((size_t)b * TT + 12) * YY + yy];
  }
}

// ===========================================================================
// GRU_BODY v10 (fp16 2-term): A hi/lo fp16 (precision 2^-22), W single fp16
// (2^-11). Per (g,ntl,rf): acc = ah*w + al*w = 2 MFMAs (was 3 bf16 terms).
// W staging 12 KiB/kt (was 24); LDS 24 KiB dbuf; same proven v7 pipeline
// (reg-staged W, dist-1 A prefetch, one full-drain barrier per kt).
// Expects in scope: tid,w,l,lr,lq,kq,cw,m0, A1h,A1l,lda1r,KT1r,
// W1p,W2p,b1p,b2p, HPh,HPl,HOh,HOl, zero_h, Bl[2][12][512].
// ===========================================================================
#define GRU_BODY()                                                            \
  const int KT2 = zero_h ? 0 : 16;                                            \
  const f32x4 vzero = {0.f, 0.f, 0.f, 0.f};                                   \
  f32x4 arz[2][2][4];                                                         \
  f32x4 axn[2][4], ahn[2][4];                                                 \
  _Pragma("unroll")                                                           \
  for (int rf = 0; rf < 2; ++rf)                                              \
    _Pragma("unroll")                                                         \
    for (int ntl = 0; ntl < 4; ++ntl) {                                       \
      arz[rf][0][ntl] = vzero; arz[rf][1][ntl] = vzero;                       \
      axn[rf][ntl] = vzero; ahn[rf][ntl] = vzero;                             \
    }                                                                         \
  int tl2a[3];                                                                \
  size_t soff[3];                                                             \
  _Pragma("unroll")                                                           \
  for (int r = 0; r < 3; ++r) {                                               \
    const int tl2 = r * 4 + w;          /* 12 tiles = g*4+ntl */              \
    const int g = tl2 >> 2, ntl = tl2 & 3;                                    \
    const int ntg = g * 32 + (cw >> 4) + ntl;                                 \
    tl2a[r] = tl2;                                                            \
    soff[r] = ((size_t)ntg * 64 + l) * 8;                                     \
  }                                                                           \
  auto stage_load = [&](const _Float16* W, int ktW, f16x8 (&v)[3]) {          \
    _Pragma("unroll")                                                         \
    for (int r = 0; r < 3; ++r)                                               \
      v[r] = ldh(W + soff[r] + (size_t)ktW * (NT * 512));                     \
  };                                                                          \
  auto stage_write = [&](f16x8 (&v)[3], int buf) {                            \
    _Pragma("unroll")                                                         \
    for (int r = 0; r < 3; ++r)                                               \
      *(f16x8*)(&Bl[buf][tl2a[r]][l * 8]) = v[r];                             \
  };                                                                          \
  auto aload = [&](const _Float16* Ah, const _Float16* Al, int lda, int ktA,  \
                   f16x8 (&d)[2][2]) {                                        \
    _Pragma("unroll")                                                         \
    for (int rf = 0; rf < 2; ++rf) {                                          \
      const size_t ao = (size_t)(m0 + rf * 16 + lr) * lda + ktA * 32 + kq;    \
      d[rf][0] = ldh(Ah + ao);                                                \
      d[rf][1] = ldh(Al + ao);                                                \
    }                                                                         \
  };                                                                          \
  auto compute = [&](f16x8 (&a)[2][2], int buf, f32x4 (&an)[2][4]) {          \
    _Pragma("unroll")                                                         \
    for (int g = 0; g < 3; ++g)                                               \
      _Pragma("unroll")                                                       \
      for (int ntl = 0; ntl < 4; ++ntl) {                                     \
        f16x8 wv = *(const f16x8*)(&Bl[buf][g * 4 + ntl][l * 8]);             \
        _Pragma("unroll")                                                     \
        for (int rf = 0; rf < 2; ++rf) {                                      \
          if (g < 2)                                                          \
            arz[rf][g][ntl] = mh(a[rf][1], wv,                                \
                                 mh(a[rf][0], wv, arz[rf][g][ntl]));          \
          else                                                                \
            an[rf][ntl] = mh(a[rf][1], wv,                                    \
                             mh(a[rf][0], wv, an[rf][ntl]));                  \
        }                                                                     \
      }                                                                       \
  };                                                                          \
  auto acopy = [&](f16x8 (&dst)[2][2], f16x8 (&src)[2][2]) {                  \
    _Pragma("unroll")                                                         \
    for (int rf = 0; rf < 2; ++rf) {                                          \
      dst[rf][0] = src[rf][0];                                                \
      dst[rf][1] = src[rf][1];                                                \
    }                                                                         \
  };                                                                          \
  f16x8 w0[3], w1[3], acur[2][2], anx[2][2];                                  \
  stage_load(W1p, 0, w0);                                                     \
  aload(A1h, A1l, lda1r, 0, acur);                                            \
  stage_write(w0, 0);                                                         \
  __syncthreads();                                                            \
  for (int kt = 0; kt < KT1r; ++kt) {                                         \
    const int buf = kt & 1;                                                   \
    const bool more1 = (kt + 1 < KT1r);                                       \
    const bool next = more1 || (KT2 > 0);                                     \
    if (more1)      { stage_load(W1p, kt + 1, w1); aload(A1h, A1l, lda1r, kt + 1, anx); } \
    else if (KT2)   { stage_load(W2p, 0, w1);      aload(HPh, HPl, HH, 0, anx); }         \
    compute(acur, buf, axn);                                                  \
    if (next) stage_write(w1, buf ^ 1);                                       \
    __syncthreads();                                                          \
    if (next) acopy(acur, anx);                                               \
  }                                                                           \
  if (KT2) {                                                                  \
    for (int kt = 0; kt < 16; ++kt) {                                         \
      const int buf = (KT1r + kt) & 1;                                        \
      const bool next = (kt + 1 < 16);                                        \
      if (next) { stage_load(W2p, kt + 1, w1); aload(HPh, HPl, HH, kt + 1, anx); } \
      compute(acur, buf, ahn);                                                \
      if (next) stage_write(w1, buf ^ 1);                                     \
      __syncthreads();                                                        \
      if (next) acopy(acur, anx);                                             \
    }                                                                         \
  }                                                                           \
  _Pragma("unroll")                                                           \
  for (int ntl = 0; ntl < 4; ++ntl) {                                         \
    const int col = cw + ntl * 16 + lr;                                       \
    const float bx0 = b1p[col], bx1 = b1p[col + HH], bx2 = b1p[col + 2 * HH]; \
    const float bh0 = b2p[col], bh1 = b2p[col + HH], bh2 = b2p[col + 2 * HH]; \
    _Pragma("unroll")                                                         \
    for (int rf = 0; rf < 2; ++rf)                                            \
      _Pragma("unroll")                                                       \
      for (int i = 0; i < 4; ++i) {                                           \
        const int row = m0 + rf * 16 + lq * 4 + i;                            \
        const float rr = sigf(arz[rf][0][ntl][i] + bx0 + bh0);                \
        const float zz = sigf(arz[rf][1][ntl][i] + bx1 + bh1);                \
        const float nn = tanhf(axn[rf][ntl][i] + bx2 + rr * (ahn[rf][ntl][i] + bh2)); \
        float hp = 0.f;                                                       \
        const size_t hidx = (size_t)row * HH + col;                           \
        if (!zero_h)                                                          \
          hp = (float)HPh[hidx] + (float)HPl[hidx];                           \
        const float hn = (1.f - zz) * nn + zz * hp;                           \
        _Float16 sh, sl;                                                      \
        split2h(hn, sh, sl);                                                  \
        HOh[hidx] = sh;                                                       \
        HOl[hidx] = sl;                                                       \
      }                                                                       \
  }

// ---------------------------------------------------------------------------
// gru2: single-layer kernel (128x64 tile, R6 grid orientation: x=colgroup
// -> XCD-local W in L2). fp16 2-term. LDS 24 KiB -> 3 blocks/CU.
// ---------------------------------------------------------------------------
template <int KT1>
__global__ __launch_bounds__(256, 3) void gru2(
    const _Float16* __restrict__ a1h, const _Float16* __restrict__ a1l, int lda1,
    const _Float16* __restrict__ W1, const float* __restrict__ b1,
    const _Float16* __restrict__ hbh, const _Float16* __restrict__ hbl,
    const _Float16* __restrict__ W2, const float* __restrict__ b2,
    _Float16* __restrict__ obh, _Float16* __restrict__ obl,
    GruPhase ph)
{
  __shared__ __align__(16) _Float16 Bl[2][12][512];
  const int tid = threadIdx.x;
  const int w = tid >> 6, l = tid & 63;
  const int lr = l & 15, lq = l >> 4, kq = lq * 8;
  const int cell = blockIdx.y >> 3, rt = blockIdx.y & 7;
  const int cw = blockIdx.x * 64;
  const int m0 = rt * 128 + w * 32;
  const _Float16* A1h = a1h + ph.a1off[cell];
  const _Float16* A1l = a1l + ph.a1off[cell];
  const _Float16* HPh = hbh + ph.hoff[cell];
  const _Float16* HPl = hbl + ph.hoff[cell];
  _Float16* HOh = obh + ph.ooff[cell];
  _Float16* HOl = obl + ph.ooff[cell];
  const int zero_h = (ph.zmask >> cell) & 1;
  const int KT1r = KT1;
  const int lda1r = lda1;
  const _Float16 *W1p = W1, *W2p = W2;
  const float *b1p = b1, *b2p = b2;
  GRU_BODY()
}

// ---------------------------------------------------------------------------
// gru2m: MERGED dual-layer dispatch, D(s) = L0(s) u L1(s-1) (R10/R11
// verified legal for all s<=12 via parity double-buffer). fp16 2-term.
// ---------------------------------------------------------------------------
__global__ __launch_bounds__(256, 3) void gru2m(
    const _Float16* __restrict__ tokh, const _Float16* __restrict__ tokl,
    _Float16* __restrict__ h0h, _Float16* __restrict__ h0l,
    _Float16* __restrict__ h1h, _Float16* __restrict__ h1l,
    const _Float16* __restrict__ W0, const _Float16* __restrict__ Wh0,
    const float* __restrict__ bi0, const float* __restrict__ bh0,
    const _Float16* __restrict__ Wi1, const _Float16* __restrict__ Wh1,
    const float* __restrict__ bi1, const float* __restrict__ bh1,
    GruPhase2 ph)
{
  __shared__ __align__(16) _Float16 Bl[2][12][512];
  const int tid = threadIdx.x;
  const int w = tid >> 6, l = tid & 63;
  const int lr = l & 15, lq = l >> 4, kq = lq * 8;
  const int cell = blockIdx.y >> 3, rt = blockIdx.y & 7;
  const int cw = blockIdx.x * 64;
  const int m0 = rt * 128 + w * 32;
  const int isL1 = (ph.laymask >> cell) & 1;
  const int KT1r = isL1 ? (HH / 32) : (YP / 32);
  const int lda1r = isL1 ? HH : YP;
  const _Float16* A1h = (isL1 ? h0h : tokh) + ph.a1off[cell];
  const _Float16* A1l = (isL1 ? h0l : tokl) + ph.a1off[cell];
  const _Float16* HPh = (isL1 ? h1h : h0h) + ph.hoff[cell];
  const _Float16* HPl = (isL1 ? h1l : h0l) + ph.hoff[cell];
  _Float16* HOh = (isL1 ? h1h : h0h) + ph.ooff[cell];
  _Float16* HOl = (isL1 ? h1l : h0l) + ph.ooff[cell];
  const _Float16* W1p = isL1 ? Wi1 : W0;
  const _Float16* W2p = isL1 ? Wh1 : Wh0;
  const float* b1p = isL1 ? bi1 : bi0;
  const float* b2p = isL1 ? bh1 : bh0;
  const int zero_h = (ph.zmask >> cell) & 1;
  GRU_BODY()
}

// ---------------------------------------------------------------------------
// gru2n (small-C path): 128x32 tile, fp16 2-term. 6 KiB W stage/kt
// (384 16B-units: r=0 all threads, r=1 tid<128). LDS 12 KiB.
// ---------------------------------------------------------------------------
template <int KT1>
__global__ __launch_bounds__(256) void gru2n(
    const _Float16* __restrict__ a1h, const _Float16* __restrict__ a1l, int lda1,
    const _Float16* __restrict__ W1, const float* __restrict__ b1,
    const _Float16* __restrict__ hbh, const _Float16* __restrict__ hbl,
    const _Float16* __restrict__ W2, const float* __restrict__ b2,
    _Float16* __restrict__ obh, _Float16* __restrict__ obl,
    GruPhase ph)
{
  __shared__ __align__(16) _Float16 Bl[2][6][512];
  const int tid = threadIdx.x;
  const int w = tid >> 6, l = tid & 63;
  const int lr = l & 15, lq = l >> 4, kq = lq * 8;
  const int cell = blockIdx.y >> 3, rt = blockIdx.y & 7;
  const int cw = blockIdx.x * 32;
  const int m0 = rt * 128 + w * 32;
  const _Float16* A1h = a1h + ph.a1off[cell];
  const _Float16* A1l = a1l + ph.a1off[cell];
  const _Float16* HPh = hbh + ph.hoff[cell];
  const _Float16* HPl = hbl + ph.hoff[cell];
  _Float16* HOh = obh + ph.ooff[cell];
  _Float16* HOl = obl + ph.ooff[cell];
  const int zero_h = (ph.zmask >> cell) & 1;
  const int KT2 = zero_h ? 0 : 16;

  const f32x4 vzero = {0.f, 0.f, 0.f, 0.f};
  f32x4 arz[2][2][2];
  f32x4 axn[2][2], ahn[2][2];
#pragma unroll
  for (int rf = 0; rf < 2; ++rf)
#pragma unroll
    for (int ntl = 0; ntl < 2; ++ntl) {
      arz[rf][0][ntl] = vzero; arz[rf][1][ntl] = vzero;
      axn[rf][ntl] = vzero; ahn[rf][ntl] = vzero;
    }

  // staging geometry: 6 tiles x 64 units = 384; r=0: u=tid; r=1: u=256+tid (tid<128)
  const bool act1 = (tid < 128);
  int tl2a[2], uia[2];
  size_t soff[2];
#pragma unroll
  for (int r = 0; r < 2; ++r) {
    int u = r * 256 + tid;
    int tl2 = (u >> 6) % 6;
    int ui = u & 63;
    int g = tl2 >> 1, ntl = tl2 & 1;
    int ntg = g * 32 + (cw >> 4) + ntl;
    tl2a[r] = tl2; uia[r] = ui;
    soff[r] = ((size_t)ntg * 64 + ui) * 8;
  }

  auto stage_load = [&](const _Float16* W, int ktW, f16x8 (&v)[2]) {
    v[0] = ldh(W + soff[0] + (size_t)ktW * (NT * 512));
    if (act1) v[1] = ldh(W + soff[1] + (size_t)ktW * (NT * 512));
  };
  auto stage_write = [&](f16x8 (&v)[2], int buf) {
    *(f16x8*)(&Bl[buf][tl2a[0]][uia[0] * 8]) = v[0];
    if (act1) *(f16x8*)(&Bl[buf][tl2a[1]][uia[1] * 8]) = v[1];
  };
  auto aload = [&](const _Float16* Ah, const _Float16* Al, int lda, int ktA,
                   f16x8 (&d)[2][2]) {
#pragma unroll
    for (int rf = 0; rf < 2; ++rf) {
      const size_t ao = (size_t)(m0 + rf * 16 + lr) * lda + ktA * 32 + kq;
      d[rf][0] = ldh(Ah + ao);
      d[rf][1] = ldh(Al + ao);
    }
  };
  auto compute = [&](f16x8 (&a)[2][2], int buf, f32x4 (&an)[2][2]) {
#pragma unroll
    for (int g = 0; g < 3; ++g)
#pragma unroll
      for (int ntl = 0; ntl < 2; ++ntl) {
        f16x8 wv = *(const f16x8*)(&Bl[buf][g * 2 + ntl][l * 8]);
#pragma unroll
        for (int rf = 0; rf < 2; ++rf) {
          if (g < 2)
            arz[rf][g][ntl] = mh(a[rf][1], wv, mh(a[rf][0], wv, arz[rf][g][ntl]));
          else
            an[rf][ntl] = mh(a[rf][1], wv, mh(a[rf][0], wv, an[rf][ntl]));
        }
      }
  };
  auto acopy = [&](f16x8 (&dst)[2][2], f16x8 (&src)[2][2]) {
#pragma unroll
    for (int rf = 0; rf < 2; ++rf) {
      dst[rf][0] = src[rf][0];
      dst[rf][1] = src[rf][1];
    }
  };

  f16x8 w0[2], w1[2], acur[2][2], anx[2][2];

  stage_load(W1, 0, w0);
  aload(A1h, A1l, lda1, 0, acur);
  stage_write(w0, 0);
  __syncthreads();

  for (int kt = 0; kt < KT1; ++kt) {
    const int buf = kt & 1;
    const bool more1 = (kt + 1 < KT1);
    const bool next = more1 || (KT2 > 0);
    if (more1)      { stage_load(W1, kt + 1, w1); aload(A1h, A1l, lda1, kt + 1, anx); }
    else if (KT2)   { stage_load(W2, 0, w1);      aload(HPh, HPl, HH, 0, anx); }
    compute(acur, buf, axn);
    if (next) stage_write(w1, buf ^ 1);
    __syncthreads();
    if (next) acopy(acur, anx);
  }
  if (KT2) {
    for (int kt = 0; kt < 16; ++kt) {
      const int buf = (KT1 + kt) & 1;
      const bool next = (kt + 1 < 16);
      if (next) { stage_load(W2, kt + 1, w1); aload(HPh, HPl, HH, kt + 1, anx); }
      compute(acur, buf, ahn);
      if (next) stage_write(w1, buf ^ 1);
      __syncthreads();
      if (next) acopy(acur, anx);
    }
  }

#pragma unroll
  for (int ntl = 0; ntl < 2; ++ntl) {
    const int col = cw + ntl * 16 + lr;
    const float bx0 = b1[col], bx1 = b1[col + HH], bx2 = b1[col + 2 * HH];
    const float bh0 = b2[col], bh1 = b2[col + HH], bh2 = b2[col + 2 * HH];
#pragma unroll
    for (int rf = 0; rf < 2; ++rf)
#pragma unroll
      for (int i = 0; i < 4; ++i) {
        const int row = m0 + rf * 16 + lq * 4 + i;
        const float rr = sigf(arz[rf][0][ntl][i] + bx0 + bh0);
        const float zz = sigf(arz[rf][1][ntl][i] + bx1 + bh1);
        const float nn = tanhf(axn[rf][ntl][i] + bx2 + rr * (ahn[rf][ntl][i] + bh2));
        float hp = 0.f;
        const size_t hidx = (size_t)row * HH + col;
        if (!zero_h)
          hp = (float)HPh[hidx] + (float)HPl[hidx];
        const float hn = (1.f - zz) * nn + zz * hp;
        _Float16 sh, sl;
        split2h(hn, sh, sl);
        HOh[hidx] = sh;
        HOl[hidx] = sl;
      }
  }
}

// ---------------------------------------------------------------------------
// Output projection (MFMA, bf16 3-term unchanged): o = relu(h1)@W_out^T
// + b_out + res. h1 inputs now fp16 hi/lo. grid(6,8) = 48 blocks.
// ---------------------------------------------------------------------------
__global__ __launch_bounds__(256) void out_m(
    const _Float16* __restrict__ h1h, const _Float16* __restrict__ h1l,
    const bf16* __restrict__ Wh, const bf16* __restrict__ Wl,
    const float* __restrict__ bo,
    float* __restrict__ res,
    _Float16* __restrict__ yh, _Float16* __restrict__ yl,
    float* __restrict__ outp, int d)
{
  const int tid = threadIdx.x;
  const int w = tid >> 6, l = tid & 63;
  const int lr = l & 15, lq = l >> 4, kq = lq * 8;
  const int m0 = blockIdx.y * 128 + w * 32;
  const int cw = blockIdx.x * 32;

  const f32x4 vzero = {0.f, 0.f, 0.f, 0.f};
  f32x4 acc[2][2];
#pragma unroll
  for (int rf = 0; rf < 2; ++rf)
#pragma unroll
    for (int ntl = 0; ntl < 2; ++ntl) acc[rf][ntl] = vzero;

  for (int kt = 0; kt < HH / 32; ++kt) {
    bf16x8 ah[2], al[2];
#pragma unroll
    for (int rf = 0; rf < 2; ++rf) {
      const size_t ao = (size_t)(m0 + rf * 16 + lr) * HH + kt * 32 + kq;
      f16x8 hh = ldh(h1h + ao);
      f16x8 hl = ldh(h1l + ao);
#pragma unroll
      for (int j = 0; j < 8; ++j) {
        float v = fmaxf((float)hh[j] + (float)hl[j], 0.f);
        __bf16 vh = (__bf16)v;
        __bf16 vl = (__bf16)(v - (float)vh);
        ah[rf][j] = vh;
        al[rf][j] = vl;
      }
    }
#pragma unroll
    for (int ntl = 0; ntl < 2; ++ntl) {
      const int nt = (cw >> 4) + ntl;
      const size_t bo_ = ((size_t)(kt * NTO + nt) * 64 + l) * 8;
      bf16x8 bh = ldf(Wh + bo_);
      bf16x8 bl = ldf(Wl + bo_);
#pragma unroll
      for (int rf = 0; rf < 2; ++rf)
        acc[rf][ntl] = mf(ah[rf], bl, mf(al[rf], bh,
                          mf(ah[rf], bh, acc[rf][ntl])));
    }
  }

#pragma unroll
  for (int ntl = 0; ntl < 2; ++ntl) {
    const int col = cw + ntl * 16 + lr;
    if (col >= YY) continue;           // padded cols 188..191: no writes
    const float bc = bo[col];
#pragma unroll
    for (int rf = 0; rf < 2; ++rf)
#pragma unroll
      for (int i = 0; i < 4; ++i) {
        const int row = m0 + rf * 16 + lq * 4 + i;
        const int ridx = row * YY + col;
        float o = acc[rf][ntl][i] + bc + res[ridx];
        res[ridx] = o;
        outp[((size_t)row * DS + d) * YY + col] = o;
        _Float16 sh, sl;
        split2h(o, sh, sl);
        yh[(size_t)row * YP + col] = sh;
        yl[(size_t)row * YP + col] = sl;
      }
  }
}

extern "C" void kernel_launch(void* const* d_in, const int* in_sizes, int n_in,
                              void* d_out, int out_size, void* d_ws, size_t ws_size,
                              hipStream_t stream)
{
  // role mapping insurance (dict-order signature, greedy fallback)
  static const int sig_dict[11] = {2501632, 288768, 786432, 1536, 1536,
                                   786432, 786432, 1536, 1536, 96256, 188};
  int map[11];
  bool dict_ok = (n_in == 11);
  if (dict_ok)
    for (int r = 0; r < 11; ++r)
      if (in_sizes[r] != sig_dict[r]) { dict_ok = false; break; }
  if (dict_ok) { for (int r = 0; r < 11; ++r) map[r] = r; }
  else {
    bool used[16] = {};
    for (int r = 0; r < 11; ++r) {
      map[r] = r < n_in ? r : 0;
      for (int i = 0; i < n_in && i < 16; ++i)
        if (!used[i] && in_sizes[i] == sig_dict[r]) { map[r] = i; used[i] = true; break; }
    }
  }
  const float* x     = (const float*)d_in[map[0]];
  const float* W_ih0 = (const float*)d_in[map[1]];
  const float* W_hh0 = (const float*)d_in[map[2]];
  const float* b_ih0 = (const float*)d_in[map[3]];
  const float* b_hh0 = (const float*)d_in[map[4]];
  const float* W_ih1 = (const float*)d_in[map[5]];
  const float* W_hh1 = (const float*)d_in[map[6]];
  const float* b_ih1 = (const float*)d_in[map[7]];
  const float* b_hh1 = (const float*)d_in[map[8]];
  const float* W_out = (const float*)d_in[map[9]];
  const float* b_out = (const float*)d_in[map[10]];
  float* outp = (float*)d_out;

  const int S    = (ws_size >= (size_t)160 << 20) ? 13 : 7;
  const int SKEW = (S == 13) ? 1 : 2;
  const int NPH  = 12 * SKEW + 13;

  char* p = (char*)d_ws;
  auto alloc = [&](size_t bytes) { char* q = p; p += (bytes + 255) & ~(size_t)255; return q; };
  _Float16* tokh = (_Float16*)alloc((size_t)26 * BB * YP * 2);
  _Float16* tokl = (_Float16*)alloc((size_t)26 * BB * YP * 2);
  _Float16* W0  = (_Float16*)alloc((size_t)GG * YP * 2);
  _Float16* Wh0 = (_Float16*)alloc((size_t)GG * HH * 2);
  _Float16* Wi1 = (_Float16*)alloc((size_t)GG * HH * 2);
  _Float16* Wh1 = (_Float16*)alloc((size_t)GG * HH * 2);
  bf16* Woh  = (bf16*)alloc((size_t)YP * HH * 2);   // W_out frags (bf16 hi/lo)
  bf16* Wol  = (bf16*)alloc((size_t)YP * HH * 2);
  _Float16* h0h = (_Float16*)alloc((size_t)2 * S * BB * HH * 2);  // parity x slot
  _Float16* h0l = (_Float16*)alloc((size_t)2 * S * BB * HH * 2);
  _Float16* h1h = (_Float16*)alloc((size_t)2 * S * BB * HH * 2);
  _Float16* h1l = (_Float16*)alloc((size_t)2 * S * BB * HH * 2);
  float* res = (float*)alloc((size_t)BB * YY * 4);

  k_setup<<<(26 * BB * YP + 255) / 256, 256, 0, stream>>>(x, tokh, tokl, res);
  k_swzh<<<NT * (YP / 32) * 64 / 256, 256, 0, stream>>>(W_ih0, W0, GG, YY, NT);
  k_swzh<<<NT * (HH / 32) * 64 / 256, 256, 0, stream>>>(W_hh0, Wh0, GG, HH, NT);
  k_swzh<<<NT * (HH / 32) * 64 / 256, 256, 0, stream>>>(W_ih1, Wi1, GG, HH, NT);
  k_swzh<<<NT * (HH / 32) * 64 / 256, 256, 0, stream>>>(W_hh1, Wh1, GG, HH, NT);
  k_swz2<<<NTO * (HH / 32) * 64 / 256, 256, 0, stream>>>(W_out, Woh, Wol, YY, HH, NTO);

  // phase cell-table builder (single-layer structs, SKEW-general)
  auto buildPhase = [&](int phs, GruPhase& P0, GruPhase& P1) {
    P0 = GruPhase{}; P1 = GruPhase{};
    const int pprev = (phs + 1) & 1, pcur = phs & 1;
    int C = 0;
    for (int d = 0; d < DS; ++d) {
      int t = phs - SKEW * d;
      if (t < 0 || t > 12) continue;
      int c = C++;
      P0.a1off[c] = (unsigned)((d + t) * BB * YP);
      P0.hoff[c]  = (unsigned)((pprev * S + d % S) * BB * HH);
      P0.ooff[c]  = (unsigned)((pcur * S + d % S) * BB * HH);
      if (t == 0) P0.zmask |= 1 << c;
      P1.a1off[c] = P0.ooff[c];
      P1.hoff[c]  = P0.hoff[c];
      P1.ooff[c]  = P0.ooff[c];
    }
    P0.ncells = P1.ncells = C;
    P1.zmask = P0.zmask;
    return C;
  };
  auto launchL0 = [&](const GruPhase& P0, int C) {
    if (C <= 5) {
      gru2n<YP / 32><<<dim3(16, C * 8), 256, 0, stream>>>(
          tokh, tokl, YP, W0, b_ih0, h0h, h0l, Wh0, b_hh0, h0h, h0l, P0);
    } else {
      gru2<YP / 32><<<dim3(8, C * 8), 256, 0, stream>>>(
          tokh, tokl, YP, W0, b_ih0, h0h, h0l, Wh0, b_hh0, h0h, h0l, P0);
    }
  };
  auto launchL1 = [&](const GruPhase& P1, int C) {
    if (C <= 5) {
      gru2n<HH / 32><<<dim3(16, C * 8), 256, 0, stream>>>(
          h0h, h0l, HH, Wi1, b_ih1, h1h, h1l, Wh1, b_hh1, h1h, h1l, P1);
    } else {
      gru2<HH / 32><<<dim3(8, C * 8), 256, 0, stream>>>(
          h0h, h0l, HH, Wi1, b_ih1, h1h, h1l, Wh1, b_hh1, h1h, h1l, P1);
    }
  };
  auto launchOut = [&](int d) {
    const int pph = 12 + SKEW * d;
    const size_t hoff = (size_t)((pph & 1) * S + d % S) * BB * HH;
    out_m<<<dim3(6, 8), 256, 0, stream>>>(
        h1h + hoff, h1l + hoff, Woh, Wol, b_out, res,
        tokh + (size_t)(13 + d) * BB * YP, tokl + (size_t)(13 + d) * BB * YP,
        outp, d);
  };

  if (SKEW == 1) {
    // ---- merged wavefront D(s) = L0(s) + L1(s-1), s=0..12
    for (int s = 0; s <= 12; ++s) {
      GruPhase2 M{};
      int c = 0;
      {  // L0 cells of phase s
        const int pprev = (s + 1) & 1, pcur = s & 1;
        for (int d = 0; d < DS; ++d) {
          int t = s - d;
          if (t < 0 || t > 12) continue;
          M.a1off[c] = (unsigned)((d + t) * BB * YP);
          M.hoff[c]  = (unsigned)((pprev * S + d % S) * BB * HH);
          M.ooff[c]  = (unsigned)((pcur * S + d % S) * BB * HH);
          if (t == 0) M.zmask |= 1u << c;
          ++c;
        }
      }
      {  // L1 cells of phase s-1 (empty at s=0)
        const int pp = s - 1;
        const int pprev = (pp + 1) & 1, pcur = pp & 1;
        for (int d = 0; d < DS; ++d) {
          int t = pp - d;
          if (t < 0 || t > 12) continue;
          M.laymask |= 1u << c;
          M.a1off[c] = (unsigned)((pcur * S + d % S) * BB * HH);  // L0(pp) out
          M.hoff[c]  = (unsigned)((pprev * S + d % S) * BB * HH);
          M.ooff[c]  = (unsigned)((pcur * S + d % S) * BB * HH);
          if (t == 0) M.zmask |= 1u << c;
          ++c;
        }
      }
      M.ncells = c;
      gru2m<<<dim3(8, c * 8), 256, 0, stream>>>(
          tokh, tokl, h0h, h0l, h1h, h1l,
          W0, Wh0, b_ih0, b_hh0, Wi1, Wh1, b_ih1, b_hh1, M);
    }
    // ---- L1(12) standalone (C=13)
    {
      GruPhase P0, P1;
      int C = buildPhase(12, P0, P1);
      launchL1(P1, C);
    }
    // ---- decode: serial chain out_m(d) -> L0(13+d) -> L1(13+d)
    for (int d = 0; d <= 12; ++d) {
      launchOut(d);
      if (d < 12) {
        GruPhase P0, P1;
        int C = buildPhase(13 + d, P0, P1);
        launchL0(P0, C);
        launchL1(P1, C);
      }
    }
  } else {
    // SKEW=2 fallback: proven R6-style schedule (no merge)
    for (int phs = 0; phs < NPH; ++phs) {
      GruPhase P0, P1;
      int C = buildPhase(phs, P0, P1);
      launchL0(P0, C);
      launchL1(P1, C);
      if (phs >= 12 && (phs - 12) % SKEW == 0) launchOut((phs - 12) / SKEW);
    }
  }
}

// Round 13
// 3394.017 us; speedup vs baseline: 1.1863x; 1.1440x over previous
//
#include <hip/hip_runtime.h>
#include <hip/hip_bf16.h>
#include <math.h>

using bf16 = __hip_bfloat16;

#define BB 1024
#define TT 13
#define YY 188
#define HH 512
#define GG 1536
#define YP 192
#define DS 13
#define NT 96    // GG/16 B-tiles along the gate dimension
#define NTO 12   // YP/16 B-tiles for the output projection

typedef __bf16 bf16x8 __attribute__((ext_vector_type(8)));
typedef _Float16 f16x8 __attribute__((ext_vector_type(8)));
typedef float f32x4 __attribute__((ext_vector_type(4)));
typedef float f4 __attribute__((ext_vector_type(4)));

__device__ __forceinline__ float sigf(float x) { return 1.f / (1.f + expf(-x)); }
__device__ __forceinline__ bf16x8 ldf(const bf16* p) {
  return *reinterpret_cast<const bf16x8*>(p);
}
__device__ __forceinline__ f16x8 ldh(const _Float16* p) {
  return *reinterpret_cast<const f16x8*>(p);
}
__device__ __forceinline__ f32x4 mf(bf16x8 a, bf16x8 b, f32x4 c) {
  return __builtin_amdgcn_mfma_f32_16x16x32_bf16(a, b, c, 0, 0, 0);
}
__device__ __forceinline__ f32x4 mh(f16x8 a, f16x8 b, f32x4 c) {
  return __builtin_amdgcn_mfma_f32_16x16x32_f16(a, b, c, 0, 0, 0);
}
__device__ __forceinline__ void split2(float v, bf16& hi, bf16& lo) {
  hi = __float2bfloat16(v);
  lo = __float2bfloat16(v - __bfloat162float(hi));
}
__device__ __forceinline__ void split2h(float v, _Float16& hi, _Float16& lo) {
  hi = (_Float16)v;
  lo = (_Float16)(v - (float)hi);
}

// Per-phase cell table (single-layer dispatches), passed by value.
struct GruPhase {
  int ncells;
  int zmask;             // bit c: t==0 (skip gh GEMM, h_prev = 0)
  unsigned a1off[13];    // A1 element offset per cell
  unsigned hoff[13];     // h_prev element offset per cell
  unsigned ooff[13];     // h_out  element offset per cell
};

// Merged dual-layer cell table (<=25 cells: L0(s) + L1(s-1)), by value.
struct GruPhase2 {
  int ncells;
  unsigned zmask;        // bit c: t==0 cell
  unsigned laymask;      // bit c: cell is layer-1
  unsigned a1off[25];
  unsigned hoff[25];
  unsigned ooff[25];
};

// ---------------------------------------------------------------------------
// k_swzh: swizzle a row-major (Nsrc x Ksrc) fp32 weight into KT-MAJOR MFMA
// B-frag order as SINGLE fp16 (W precision 2^-11 rel; the 2-term fp16
// scheme keeps A at 2^-22 via hi/lo). Tile (kt,nt) at elem
// (kt*ntiles+nt)*512; lane l holds W[nt*16+(l&15)][kt*32+(l>>4)*8+j].
// ---------------------------------------------------------------------------
__global__ void k_swzh(const float* __restrict__ src, _Float16* __restrict__ dh,
                       int Nsrc, int Ksrc, int ntiles) {
  int idx = blockIdx.x * 256 + threadIdx.x;   // ((kt*ntiles+nt), lane)
  int l = idx & 63;
  int ktnt = idx >> 6;
  int nt = ktnt % ntiles, kt = ktnt / ntiles;
  int n = nt * 16 + (l & 15);
  int k0 = kt * 32 + (l >> 4) * 8;
#pragma unroll
  for (int j = 0; j < 8; ++j) {
    int k = k0 + j;
    float v = (n < Nsrc && k < Ksrc) ? src[(size_t)n * Ksrc + k] : 0.f;
    dh[(size_t)idx * 8 + j] = (_Float16)v;
  }
}

// k_swz2: bf16 hi/lo swizzle -- retained for W_out (out_m keeps 3-term bf16).
__global__ void k_swz2(const float* __restrict__ src, bf16* __restrict__ dhi,
                       bf16* __restrict__ dlo, int Nsrc, int Ksrc, int ntiles) {
  int idx = blockIdx.x * 256 + threadIdx.x;
  int l = idx & 63;
  int ktnt = idx >> 6;
  int nt = ktnt % ntiles, kt = ktnt / ntiles;
  int n = nt * 16 + (l & 15);
  int k0 = kt * 32 + (l >> 4) * 8;
#pragma unroll
  for (int j = 0; j < 8; ++j) {
    int k = k0 + j;
    float v = (n < Nsrc && k < Ksrc) ? src[(size_t)n * Ksrc + k] : 0.f;
    bf16 h, lo;
    split2(v, h, lo);
    dhi[(size_t)idx * 8 + j] = h;
    dlo[(size_t)idx * 8 + j] = lo;
  }
}

// Setup: 26-slot hi/lo fp16 token buffers, fp32 residual from x[:,12,:].
__global__ void k_setup(const float* __restrict__ x, _Float16* __restrict__ th,
                        _Float16* __restrict__ tl, float* __restrict__ res) {
  int idx = blockIdx.x * 256 + threadIdx.x;
  const int total = 26 * BB * YP;
  if (idx < total) {
    int k = idx % YP;
    int b = (idx / YP) % BB;
    int s = idx / (YP * BB);
    float v = 0.f;
    if (s < TT && k < YY) v = x[((size_t)b * TT + s) * YY + k];
    _Float16 h, lo;
    split2h(v, h, lo);
    th[idx] = h; tl[idx] = lo;
  }
  if (idx < BB * YY) {
    int yy = idx % YY;
    int b = idx / YY;
    res[idx] = x[((size_t)b * TT + 12) * YY + yy];
  }
}

// ===========================================================================
// GRU_BODY (fp16 2-term): A hi/lo fp16 (precision 2^-22), W single fp16
// (2^-11). Per (g,ntl,rf): acc = ah*w + al*w = 2 MFMAs. W staging 12 KiB/kt;
// LDS 24 KiB dbuf; proven v7 pipeline (reg-staged W, dist-1 A prefetch,
// one full-drain barrier per kt).
// ===========================================================================
#define GRU_BODY()                                                            \
  const int KT2 = zero_h ? 0 : 16;                                            \
  const f32x4 vzero = {0.f, 0.f, 0.f, 0.f};                                   \
  f32x4 arz[2][2][4];                                                         \
  f32x4 axn[2][4], ahn[2][4];                                                 \
  _Pragma("unroll")                                                           \
  for (int rf = 0; rf < 2; ++rf)                                              \
    _Pragma("unroll")                                                         \
    for (int ntl = 0; ntl < 4; ++ntl) {                                       \
      arz[rf][0][ntl] = vzero; arz[rf][1][ntl] = vzero;                       \
      axn[rf][ntl] = vzero; ahn[rf][ntl] = vzero;                             \
    }                                                                         \
  int tl2a[3];                                                                \
  size_t soff[3];                                                             \
  _Pragma("unroll")                                                           \
  for (int r = 0; r < 3; ++r) {                                               \
    const int tl2 = r * 4 + w;          /* 12 tiles = g*4+ntl */              \
    const int g = tl2 >> 2, ntl = tl2 & 3;                                    \
    const int ntg = g * 32 + (cw >> 4) + ntl;                                 \
    tl2a[r] = tl2;                                                            \
    soff[r] = ((size_t)ntg * 64 + l) * 8;                                     \
  }                                                                           \
  auto stage_load = [&](const _Float16* W, int ktW, f16x8 (&v)[3]) {          \
    _Pragma("unroll")                                                         \
    for (int r = 0; r < 3; ++r)                                               \
      v[r] = ldh(W + soff[r] + (size_t)ktW * (NT * 512));                     \
  };                                                                          \
  auto stage_write = [&](f16x8 (&v)[3], int buf) {                            \
    _Pragma("unroll")                                                         \
    for (int r = 0; r < 3; ++r)                                               \
      *(f16x8*)(&Bl[buf][tl2a[r]][l * 8]) = v[r];                             \
  };                                                                          \
  auto aload = [&](const _Float16* Ah, const _Float16* Al, int lda, int ktA,  \
                   f16x8 (&d)[2][2]) {                                        \
    _Pragma("unroll")                                                         \
    for (int rf = 0; rf < 2; ++rf) {                                          \
      const size_t ao = (size_t)(m0 + rf * 16 + lr) * lda + ktA * 32 + kq;    \
      d[rf][0] = ldh(Ah + ao);                                                \
      d[rf][1] = ldh(Al + ao);                                                \
    }                                                                         \
  };                                                                          \
  auto compute = [&](f16x8 (&a)[2][2], int buf, f32x4 (&an)[2][4]) {          \
    _Pragma("unroll")                                                         \
    for (int g = 0; g < 3; ++g)                                               \
      _Pragma("unroll")                                                       \
      for (int ntl = 0; ntl < 4; ++ntl) {                                     \
        f16x8 wv = *(const f16x8*)(&Bl[buf][g * 4 + ntl][l * 8]);             \
        _Pragma("unroll")                                                     \
        for (int rf = 0; rf < 2; ++rf) {                                      \
          if (g < 2)                                                          \
            arz[rf][g][ntl] = mh(a[rf][1], wv,                                \
                                 mh(a[rf][0], wv, arz[rf][g][ntl]));          \
          else                                                                \
            an[rf][ntl] = mh(a[rf][1], wv,                                    \
                             mh(a[rf][0], wv, an[rf][ntl]));                  \
        }                                                                     \
      }                                                                       \
  };                                                                          \
  auto acopy = [&](f16x8 (&dst)[2][2], f16x8 (&src)[2][2]) {                  \
    _Pragma("unroll")                                                         \
    for (int rf = 0; rf < 2; ++rf) {                                          \
      dst[rf][0] = src[rf][0];                                                \
      dst[rf][1] = src[rf][1];                                                \
    }                                                                         \
  };                                                                          \
  f16x8 w0[3], w1[3], acur[2][2], anx[2][2];                                  \
  stage_load(W1p, 0, w0);                                                     \
  aload(A1h, A1l, lda1r, 0, acur);                                            \
  stage_write(w0, 0);                                                         \
  __syncthreads();                                                            \
  for (int kt = 0; kt < KT1r; ++kt) {                                         \
    const int buf = kt & 1;                                                   \
    const bool more1 = (kt + 1 < KT1r);                                       \
    const bool next = more1 || (KT2 > 0);                                     \
    if (more1)      { stage_load(W1p, kt + 1, w1); aload(A1h, A1l, lda1r, kt + 1, anx); } \
    else if (KT2)   { stage_load(W2p, 0, w1);      aload(HPh, HPl, HH, 0, anx); }         \
    compute(acur, buf, axn);                                                  \
    if (next) stage_write(w1, buf ^ 1);                                       \
    __syncthreads();                                                          \
    if (next) acopy(acur, anx);                                               \
  }                                                                           \
  if (KT2) {                                                                  \
    for (int kt = 0; kt < 16; ++kt) {                                         \
      const int buf = (KT1r + kt) & 1;                                        \
      const bool next = (kt + 1 < 16);                                        \
      if (next) { stage_load(W2p, kt + 1, w1); aload(HPh, HPl, HH, kt + 1, anx); } \
      compute(acur, buf, ahn);                                                \
      if (next) stage_write(w1, buf ^ 1);                                     \
      __syncthreads();                                                        \
      if (next) acopy(acur, anx);                                             \
    }                                                                         \
  }                                                                           \
  _Pragma("unroll")                                                           \
  for (int ntl = 0; ntl < 4; ++ntl) {                                         \
    const int col = cw + ntl * 16 + lr;                                       \
    const float bx0 = b1p[col], bx1 = b1p[col + HH], bx2 = b1p[col + 2 * HH]; \
    const float bh0 = b2p[col], bh1 = b2p[col + HH], bh2 = b2p[col + 2 * HH]; \
    _Pragma("unroll")                                                         \
    for (int rf = 0; rf < 2; ++rf)                                            \
      _Pragma("unroll")                                                       \
      for (int i = 0; i < 4; ++i) {                                           \
        const int row = m0 + rf * 16 + lq * 4 + i;                            \
        const float rr = sigf(arz[rf][0][ntl][i] + bx0 + bh0);                \
        const float zz = sigf(arz[rf][1][ntl][i] + bx1 + bh1);                \
        const float nn = tanhf(axn[rf][ntl][i] + bx2 + rr * (ahn[rf][ntl][i] + bh2)); \
        float hp = 0.f;                                                       \
        const size_t hidx = (size_t)row * HH + col;                           \
        if (!zero_h)                                                          \
          hp = (float)HPh[hidx] + (float)HPl[hidx];                           \
        const float hn = (1.f - zz) * nn + zz * hp;                           \
        _Float16 sh, sl;                                                      \
        split2h(hn, sh, sl);                                                  \
        HOh[hidx] = sh;                                                       \
        HOl[hidx] = sl;                                                       \
      }                                                                       \
  }

// ---------------------------------------------------------------------------
// gru2: single-layer kernel (128x64 tile, R6 grid orientation). fp16 2-term.
// R13: __launch_bounds__(256,2) -- R12's (256,3) made ALL ~200 blocks of a
// merged dispatch co-resident, thrashing per-XCD L2 (FETCH 368->570 MB,
// WRITE 99->358 MB, HBM-congestion-bound). 2 blocks/CU is the validated
// working set.
// ---------------------------------------------------------------------------
template <int KT1>
__global__ __launch_bounds__(256, 2) void gru2(
    const _Float16* __restrict__ a1h, const _Float16* __restrict__ a1l, int lda1,
    const _Float16* __restrict__ W1, const float* __restrict__ b1,
    const _Float16* __restrict__ hbh, const _Float16* __restrict__ hbl,
    const _Float16* __restrict__ W2, const float* __restrict__ b2,
    _Float16* __restrict__ obh, _Float16* __restrict__ obl,
    GruPhase ph)
{
  __shared__ __align__(16) _Float16 Bl[2][12][512];
  const int tid = threadIdx.x;
  const int w = tid >> 6, l = tid & 63;
  const int lr = l & 15, lq = l >> 4, kq = lq * 8;
  const int cell = blockIdx.y >> 3, rt = blockIdx.y & 7;
  const int cw = blockIdx.x * 64;
  const int m0 = rt * 128 + w * 32;
  const _Float16* A1h = a1h + ph.a1off[cell];
  const _Float16* A1l = a1l + ph.a1off[cell];
  const _Float16* HPh = hbh + ph.hoff[cell];
  const _Float16* HPl = hbl + ph.hoff[cell];
  _Float16* HOh = obh + ph.ooff[cell];
  _Float16* HOl = obl + ph.ooff[cell];
  const int zero_h = (ph.zmask >> cell) & 1;
  const int KT1r = KT1;
  const int lda1r = lda1;
  const _Float16 *W1p = W1, *W2p = W2;
  const float *b1p = b1, *b2p = b2;
  GRU_BODY()
}

// ---------------------------------------------------------------------------
// gru2m: MERGED dual-layer dispatch, D(s) = L0(s) u L1(s-1) (R10/R11
// verified legal for all s<=12 via parity double-buffer). fp16 2-term.
// ---------------------------------------------------------------------------
__global__ __launch_bounds__(256, 2) void gru2m(
    const _Float16* __restrict__ tokh, const _Float16* __restrict__ tokl,
    _Float16* __restrict__ h0h, _Float16* __restrict__ h0l,
    _Float16* __restrict__ h1h, _Float16* __restrict__ h1l,
    const _Float16* __restrict__ W0, const _Float16* __restrict__ Wh0,
    const float* __restrict__ bi0, const float* __restrict__ bh0,
    const _Float16* __restrict__ Wi1, const _Float16* __restrict__ Wh1,
    const float* __restrict__ bi1, const float* __restrict__ bh1,
    GruPhase2 ph)
{
  __shared__ __align__(16) _Float16 Bl[2][12][512];
  const int tid = threadIdx.x;
  const int w = tid >> 6, l = tid & 63;
  const int lr = l & 15, lq = l >> 4, kq = lq * 8;
  const int cell = blockIdx.y >> 3, rt = blockIdx.y & 7;
  const int cw = blockIdx.x * 64;
  const int m0 = rt * 128 + w * 32;
  const int isL1 = (ph.laymask >> cell) & 1;
  const int KT1r = isL1 ? (HH / 32) : (YP / 32);
  const int lda1r = isL1 ? HH : YP;
  const _Float16* A1h = (isL1 ? h0h : tokh) + ph.a1off[cell];
  const _Float16* A1l = (isL1 ? h0l : tokl) + ph.a1off[cell];
  const _Float16* HPh = (isL1 ? h1h : h0h) + ph.hoff[cell];
  const _Float16* HPl = (isL1 ? h1l : h0l) + ph.hoff[cell];
  _Float16* HOh = (isL1 ? h1h : h0h) + ph.ooff[cell];
  _Float16* HOl = (isL1 ? h1l : h0l) + ph.ooff[cell];
  const _Float16* W1p = isL1 ? Wi1 : W0;
  const _Float16* W2p = isL1 ? Wh1 : Wh0;
  const float* b1p = isL1 ? bi1 : bi0;
  const float* b2p = isL1 ? bh1 : bh0;
  const int zero_h = (ph.zmask >> cell) & 1;
  GRU_BODY()
}

// ---------------------------------------------------------------------------
// gru2n (small-C path): 128x32 tile, fp16 2-term. 6 KiB W stage/kt
// (384 16B-units: r=0 all threads, r=1 tid<128). LDS 12 KiB.
// ---------------------------------------------------------------------------
template <int KT1>
__global__ __launch_bounds__(256) void gru2n(
    const _Float16* __restrict__ a1h, const _Float16* __restrict__ a1l, int lda1,
    const _Float16* __restrict__ W1, const float* __restrict__ b1,
    const _Float16* __restrict__ hbh, const _Float16* __restrict__ hbl,
    const _Float16* __restrict__ W2, const float* __restrict__ b2,
    _Float16* __restrict__ obh, _Float16* __restrict__ obl,
    GruPhase ph)
{
  __shared__ __align__(16) _Float16 Bl[2][6][512];
  const int tid = threadIdx.x;
  const int w = tid >> 6, l = tid & 63;
  const int lr = l & 15, lq = l >> 4, kq = lq * 8;
  const int cell = blockIdx.y >> 3, rt = blockIdx.y & 7;
  const int cw = blockIdx.x * 32;
  const int m0 = rt * 128 + w * 32;
  const _Float16* A1h = a1h + ph.a1off[cell];
  const _Float16* A1l = a1l + ph.a1off[cell];
  const _Float16* HPh = hbh + ph.hoff[cell];
  const _Float16* HPl = hbl + ph.hoff[cell];
  _Float16* HOh = obh + ph.ooff[cell];
  _Float16* HOl = obl + ph.ooff[cell];
  const int zero_h = (ph.zmask >> cell) & 1;
  const int KT2 = zero_h ? 0 : 16;

  const f32x4 vzero = {0.f, 0.f, 0.f, 0.f};
  f32x4 arz[2][2][2];
  f32x4 axn[2][2], ahn[2][2];
#pragma unroll
  for (int rf = 0; rf < 2; ++rf)
#pragma unroll
    for (int ntl = 0; ntl < 2; ++ntl) {
      arz[rf][0][ntl] = vzero; arz[rf][1][ntl] = vzero;
      axn[rf][ntl] = vzero; ahn[rf][ntl] = vzero;
    }

  // staging geometry: 6 tiles x 64 units = 384; r=0: u=tid; r=1: u=256+tid (tid<128)
  const bool act1 = (tid < 128);
  int tl2a[2], uia[2];
  size_t soff[2];
#pragma unroll
  for (int r = 0; r < 2; ++r) {
    int u = r * 256 + tid;
    int tl2 = (u >> 6) % 6;
    int ui = u & 63;
    int g = tl2 >> 1, ntl = tl2 & 1;
    int ntg = g * 32 + (cw >> 4) + ntl;
    tl2a[r] = tl2; uia[r] = ui;
    soff[r] = ((size_t)ntg * 64 + ui) * 8;
  }

  auto stage_load = [&](const _Float16* W, int ktW, f16x8 (&v)[2]) {
    v[0] = ldh(W + soff[0] + (size_t)ktW * (NT * 512));
    if (act1) v[1] = ldh(W + soff[1] + (size_t)ktW * (NT * 512));
  };
  auto stage_write = [&](f16x8 (&v)[2], int buf) {
    *(f16x8*)(&Bl[buf][tl2a[0]][uia[0] * 8]) = v[0];
    if (act1) *(f16x8*)(&Bl[buf][tl2a[1]][uia[1] * 8]) = v[1];
  };
  auto aload = [&](const _Float16* Ah, const _Float16* Al, int lda, int ktA,
                   f16x8 (&d)[2][2]) {
#pragma unroll
    for (int rf = 0; rf < 2; ++rf) {
      const size_t ao = (size_t)(m0 + rf * 16 + lr) * lda + ktA * 32 + kq;
      d[rf][0] = ldh(Ah + ao);
      d[rf][1] = ldh(Al + ao);
    }
  };
  auto compute = [&](f16x8 (&a)[2][2], int buf, f32x4 (&an)[2][2]) {
#pragma unroll
    for (int g = 0; g < 3; ++g)
#pragma unroll
      for (int ntl = 0; ntl < 2; ++ntl) {
        f16x8 wv = *(const f16x8*)(&Bl[buf][g * 2 + ntl][l * 8]);
#pragma unroll
        for (int rf = 0; rf < 2; ++rf) {
          if (g < 2)
            arz[rf][g][ntl] = mh(a[rf][1], wv, mh(a[rf][0], wv, arz[rf][g][ntl]));
          else
            an[rf][ntl] = mh(a[rf][1], wv, mh(a[rf][0], wv, an[rf][ntl]));
        }
      }
  };
  auto acopy = [&](f16x8 (&dst)[2][2], f16x8 (&src)[2][2]) {
#pragma unroll
    for (int rf = 0; rf < 2; ++rf) {
      dst[rf][0] = src[rf][0];
      dst[rf][1] = src[rf][1];
    }
  };

  f16x8 w0[2], w1[2], acur[2][2], anx[2][2];

  stage_load(W1, 0, w0);
  aload(A1h, A1l, lda1, 0, acur);
  stage_write(w0, 0);
  __syncthreads();

  for (int kt = 0; kt < KT1; ++kt) {
    const int buf = kt & 1;
    const bool more1 = (kt + 1 < KT1);
    const bool next = more1 || (KT2 > 0);
    if (more1)      { stage_load(W1, kt + 1, w1); aload(A1h, A1l, lda1, kt + 1, anx); }
    else if (KT2)   { stage_load(W2, 0, w1);      aload(HPh, HPl, HH, 0, anx); }
    compute(acur, buf, axn);
    if (next) stage_write(w1, buf ^ 1);
    __syncthreads();
    if (next) acopy(acur, anx);
  }
  if (KT2) {
    for (int kt = 0; kt < 16; ++kt) {
      const int buf = (KT1 + kt) & 1;
      const bool next = (kt + 1 < 16);
      if (next) { stage_load(W2, kt + 1, w1); aload(HPh, HPl, HH, kt + 1, anx); }
      compute(acur, buf, ahn);
      if (next) stage_write(w1, buf ^ 1);
      __syncthreads();
      if (next) acopy(acur, anx);
    }
  }

#pragma unroll
  for (int ntl = 0; ntl < 2; ++ntl) {
    const int col = cw + ntl * 16 + lr;
    const float bx0 = b1[col], bx1 = b1[col + HH], bx2 = b1[col + 2 * HH];
    const float bh0 = b2[col], bh1 = b2[col + HH], bh2 = b2[col + 2 * HH];
#pragma unroll
    for (int rf = 0; rf < 2; ++rf)
#pragma unroll
      for (int i = 0; i < 4; ++i) {
        const int row = m0 + rf * 16 + lq * 4 + i;
        const float rr = sigf(arz[rf][0][ntl][i] + bx0 + bh0);
        const float zz = sigf(arz[rf][1][ntl][i] + bx1 + bh1);
        const float nn = tanhf(axn[rf][ntl][i] + bx2 + rr * (ahn[rf][ntl][i] + bh2));
        float hp = 0.f;
        const size_t hidx = (size_t)row * HH + col;
        if (!zero_h)
          hp = (float)HPh[hidx] + (float)HPl[hidx];
        const float hn = (1.f - zz) * nn + zz * hp;
        _Float16 sh, sl;
        split2h(hn, sh, sl);
        HOh[hidx] = sh;
        HOl[hidx] = sl;
      }
  }
}

// ---------------------------------------------------------------------------
// Output projection (MFMA, bf16 3-term unchanged): o = relu(h1)@W_out^T
// + b_out + res. h1 inputs fp16 hi/lo. grid(6,8) = 48 blocks.
// ---------------------------------------------------------------------------
__global__ __launch_bounds__(256) void out_m(
    const _Float16* __restrict__ h1h, const _Float16* __restrict__ h1l,
    const bf16* __restrict__ Wh, const bf16* __restrict__ Wl,
    const float* __restrict__ bo,
    float* __restrict__ res,
    _Float16* __restrict__ yh, _Float16* __restrict__ yl,
    float* __restrict__ outp, int d)
{
  const int tid = threadIdx.x;
  const int w = tid >> 6, l = tid & 63;
  const int lr = l & 15, lq = l >> 4, kq = lq * 8;
  const int m0 = blockIdx.y * 128 + w * 32;
  const int cw = blockIdx.x * 32;

  const f32x4 vzero = {0.f, 0.f, 0.f, 0.f};
  f32x4 acc[2][2];
#pragma unroll
  for (int rf = 0; rf < 2; ++rf)
#pragma unroll
    for (int ntl = 0; ntl < 2; ++ntl) acc[rf][ntl] = vzero;

  for (int kt = 0; kt < HH / 32; ++kt) {
    bf16x8 ah[2], al[2];
#pragma unroll
    for (int rf = 0; rf < 2; ++rf) {
      const size_t ao = (size_t)(m0 + rf * 16 + lr) * HH + kt * 32 + kq;
      f16x8 hh = ldh(h1h + ao);
      f16x8 hl = ldh(h1l + ao);
#pragma unroll
      for (int j = 0; j < 8; ++j) {
        float v = fmaxf((float)hh[j] + (float)hl[j], 0.f);
        __bf16 vh = (__bf16)v;
        __bf16 vl = (__bf16)(v - (float)vh);
        ah[rf][j] = vh;
        al[rf][j] = vl;
      }
    }
#pragma unroll
    for (int ntl = 0; ntl < 2; ++ntl) {
      const int nt = (cw >> 4) + ntl;
      const size_t bo_ = ((size_t)(kt * NTO + nt) * 64 + l) * 8;
      bf16x8 bh = ldf(Wh + bo_);
      bf16x8 bl = ldf(Wl + bo_);
#pragma unroll
      for (int rf = 0; rf < 2; ++rf)
        acc[rf][ntl] = mf(ah[rf], bl, mf(al[rf], bh,
                          mf(ah[rf], bh, acc[rf][ntl])));
    }
  }

#pragma unroll
  for (int ntl = 0; ntl < 2; ++ntl) {
    const int col = cw + ntl * 16 + lr;
    if (col >= YY) continue;           // padded cols 188..191: no writes
    const float bc = bo[col];
#pragma unroll
    for (int rf = 0; rf < 2; ++rf)
#pragma unroll
      for (int i = 0; i < 4; ++i) {
        const int row = m0 + rf * 16 + lq * 4 + i;
        const int ridx = row * YY + col;
        float o = acc[rf][ntl][i] + bc + res[ridx];
        res[ridx] = o;
        outp[((size_t)row * DS + d) * YY + col] = o;
        _Float16 sh, sl;
        split2h(o, sh, sl);
        yh[(size_t)row * YP + col] = sh;
        yl[(size_t)row * YP + col] = sl;
      }
  }
}

extern "C" void kernel_launch(void* const* d_in, const int* in_sizes, int n_in,
                              void* d_out, int out_size, void* d_ws, size_t ws_size,
                              hipStream_t stream)
{
  // role mapping insurance (dict-order signature, greedy fallback)
  static const int sig_dict[11] = {2501632, 288768, 786432, 1536, 1536,
                                   786432, 786432, 1536, 1536, 96256, 188};
  int map[11];
  bool dict_ok = (n_in == 11);
  if (dict_ok)
    for (int r = 0; r < 11; ++r)
      if (in_sizes[r] != sig_dict[r]) { dict_ok = false; break; }
  if (dict_ok) { for (int r = 0; r < 11; ++r) map[r] = r; }
  else {
    bool used[16] = {};
    for (int r = 0; r < 11; ++r) {
      map[r] = r < n_in ? r : 0;
      for (int i = 0; i < n_in && i < 16; ++i)
        if (!used[i] && in_sizes[i] == sig_dict[r]) { map[r] = i; used[i] = true; break; }
    }
  }
  const float* x     = (const float*)d_in[map[0]];
  const float* W_ih0 = (const float*)d_in[map[1]];
  const float* W_hh0 = (const float*)d_in[map[2]];
  const float* b_ih0 = (const float*)d_in[map[3]];
  const float* b_hh0 = (const float*)d_in[map[4]];
  const float* W_ih1 = (const float*)d_in[map[5]];
  const float* W_hh1 = (const float*)d_in[map[6]];
  const float* b_ih1 = (const float*)d_in[map[7]];
  const float* b_hh1 = (const float*)d_in[map[8]];
  const float* W_out = (const float*)d_in[map[9]];
  const float* b_out = (const float*)d_in[map[10]];
  float* outp = (float*)d_out;

  const int S    = (ws_size >= (size_t)160 << 20) ? 13 : 7;
  const int SKEW = (S == 13) ? 1 : 2;
  const int NPH  = 12 * SKEW + 13;

  char* p = (char*)d_ws;
  auto alloc = [&](size_t bytes) { char* q = p; p += (bytes + 255) & ~(size_t)255; return q; };
  _Float16* tokh = (_Float16*)alloc((size_t)26 * BB * YP * 2);
  _Float16* tokl = (_Float16*)alloc((size_t)26 * BB * YP * 2);
  _Float16* W0  = (_Float16*)alloc((size_t)GG * YP * 2);
  _Float16* Wh0 = (_Float16*)alloc((size_t)GG * HH * 2);
  _Float16* Wi1 = (_Float16*)alloc((size_t)GG * HH * 2);
  _Float16* Wh1 = (_Float16*)alloc((size_t)GG * HH * 2);
  bf16* Woh  = (bf16*)alloc((size_t)YP * HH * 2);   // W_out frags (bf16 hi/lo)
  bf16* Wol  = (bf16*)alloc((size_t)YP * HH * 2);
  _Float16* h0h = (_Float16*)alloc((size_t)2 * S * BB * HH * 2);  // parity x slot
  _Float16* h0l = (_Float16*)alloc((size_t)2 * S * BB * HH * 2);
  _Float16* h1h = (_Float16*)alloc((size_t)2 * S * BB * HH * 2);
  _Float16* h1l = (_Float16*)alloc((size_t)2 * S * BB * HH * 2);
  float* res = (float*)alloc((size_t)BB * YY * 4);

  k_setup<<<(26 * BB * YP + 255) / 256, 256, 0, stream>>>(x, tokh, tokl, res);
  k_swzh<<<NT * (YP / 32) * 64 / 256, 256, 0, stream>>>(W_ih0, W0, GG, YY, NT);
  k_swzh<<<NT * (HH / 32) * 64 / 256, 256, 0, stream>>>(W_hh0, Wh0, GG, HH, NT);
  k_swzh<<<NT * (HH / 32) * 64 / 256, 256, 0, stream>>>(W_ih1, Wi1, GG, HH, NT);
  k_swzh<<<NT * (HH / 32) * 64 / 256, 256, 0, stream>>>(W_hh1, Wh1, GG, HH, NT);
  k_swz2<<<NTO * (HH / 32) * 64 / 256, 256, 0, stream>>>(W_out, Woh, Wol, YY, HH, NTO);

  // phase cell-table builder (single-layer structs, SKEW-general)
  auto buildPhase = [&](int phs, GruPhase& P0, GruPhase& P1) {
    P0 = GruPhase{}; P1 = GruPhase{};
    const int pprev = (phs + 1) & 1, pcur = phs & 1;
    int C = 0;
    for (int d = 0; d < DS; ++d) {
      int t = phs - SKEW * d;
      if (t < 0 || t > 12) continue;
      int c = C++;
      P0.a1off[c] = (unsigned)((d + t) * BB * YP);
      P0.hoff[c]  = (unsigned)((pprev * S + d % S) * BB * HH);
      P0.ooff[c]  = (unsigned)((pcur * S + d % S) * BB * HH);
      if (t == 0) P0.zmask |= 1 << c;
      P1.a1off[c] = P0.ooff[c];
      P1.hoff[c]  = P0.hoff[c];
      P1.ooff[c]  = P0.ooff[c];
    }
    P0.ncells = P1.ncells = C;
    P1.zmask = P0.zmask;
    return C;
  };
  auto launchL0 = [&](const GruPhase& P0, int C) {
    if (C <= 5) {
      gru2n<YP / 32><<<dim3(16, C * 8), 256, 0, stream>>>(
          tokh, tokl, YP, W0, b_ih0, h0h, h0l, Wh0, b_hh0, h0h, h0l, P0);
    } else {
      gru2<YP / 32><<<dim3(8, C * 8), 256, 0, stream>>>(
          tokh, tokl, YP, W0, b_ih0, h0h, h0l, Wh0, b_hh0, h0h, h0l, P0);
    }
  };
  auto launchL1 = [&](const GruPhase& P1, int C) {
    if (C <= 5) {
      gru2n<HH / 32><<<dim3(16, C * 8), 256, 0, stream>>>(
          h0h, h0l, HH, Wi1, b_ih1, h1h, h1l, Wh1, b_hh1, h1h, h1l, P1);
    } else {
      gru2<HH / 32><<<dim3(8, C * 8), 256, 0, stream>>>(
          h0h, h0l, HH, Wi1, b_ih1, h1h, h1l, Wh1, b_hh1, h1h, h1l, P1);
    }
  };
  auto launchOut = [&](int d) {
    const int pph = 12 + SKEW * d;
    const size_t hoff = (size_t)((pph & 1) * S + d % S) * BB * HH;
    out_m<<<dim3(6, 8), 256, 0, stream>>>(
        h1h + hoff, h1l + hoff, Woh, Wol, b_out, res,
        tokh + (size_t)(13 + d) * BB * YP, tokl + (size_t)(13 + d) * BB * YP,
        outp, d);
  };

  if (SKEW == 1) {
    // ---- merged wavefront D(s) = L0(s) + L1(s-1), s=0..12
    for (int s = 0; s <= 12; ++s) {
      GruPhase2 M{};
      int c = 0;
      {  // L0 cells of phase s
        const int pprev = (s + 1) & 1, pcur = s & 1;
        for (int d = 0; d < DS; ++d) {
          int t = s - d;
          if (t < 0 || t > 12) continue;
          M.a1off[c] = (unsigned)((d + t) * BB * YP);
          M.hoff[c]  = (unsigned)((pprev * S + d % S) * BB * HH);
          M.ooff[c]  = (unsigned)((pcur * S + d % S) * BB * HH);
          if (t == 0) M.zmask |= 1u << c;
          ++c;
        }
      }
      {  // L1 cells of phase s-1 (empty at s=0)
        const int pp = s - 1;
        const int pprev = (pp + 1) & 1, pcur = pp & 1;
        for (int d = 0; d < DS; ++d) {
          int t = pp - d;
          if (t < 0 || t > 12) continue;
          M.laymask |= 1u << c;
          M.a1off[c] = (unsigned)((pcur * S + d % S) * BB * HH);  // L0(pp) out
          M.hoff[c]  = (unsigned)((pprev * S + d % S) * BB * HH);
          M.ooff[c]  = (unsigned)((pcur * S + d % S) * BB * HH);
          if (t == 0) M.zmask |= 1u << c;
          ++c;
        }
      }
      M.ncells = c;
      gru2m<<<dim3(8, c * 8), 256, 0, stream>>>(
          tokh, tokl, h0h, h0l, h1h, h1l,
          W0, Wh0, b_ih0, b_hh0, Wi1, Wh1, b_ih1, b_hh1, M);
    }
    // ---- L1(12) standalone (C=13)
    {
      GruPhase P0, P1;
      int C = buildPhase(12, P0, P1);
      launchL1(P1, C);
    }
    // ---- decode: serial chain out_m(d) -> L0(13+d) -> L1(13+d)
    for (int d = 0; d <= 12; ++d) {
      launchOut(d);
      if (d < 12) {
        GruPhase P0, P1;
        int C = buildPhase(13 + d, P0, P1);
        launchL0(P0, C);
        launchL1(P1, C);
      }
    }
  } else {
    // SKEW=2 fallback: proven R6-style schedule (no merge)
    for (int phs = 0; phs < NPH; ++phs) {
      GruPhase P0, P1;
      int C = buildPhase(phs, P0, P1);
      launchL0(P0, C);
      launchL1(P1, C);
      if (phs >= 12 && (phs - 12) % SKEW == 0) launchOut((phs - 12) / SKEW);
    }
  }
}

// Round 14
// 3374.839 us; speedup vs baseline: 1.1931x; 1.0057x over previous
//
#include <hip/hip_runtime.h>
#include <hip/hip_bf16.h>
#include <math.h>

using bf16 = __hip_bfloat16;

#define BB 1024
#define TT 13
#define YY 188
#define HH 512
#define GG 1536
#define YP 192
#define DS 13
#define NT 96    // GG/16 B-tiles along the gate dimension
#define NTO 12   // YP/16 B-tiles for the output projection

typedef __bf16 bf16x8 __attribute__((ext_vector_type(8)));
typedef _Float16 f16x8 __attribute__((ext_vector_type(8)));
typedef float f32x4 __attribute__((ext_vector_type(4)));
typedef float f4 __attribute__((ext_vector_type(4)));

__device__ __forceinline__ float sigf(float x) { return 1.f / (1.f + expf(-x)); }
__device__ __forceinline__ bf16x8 ldf(const bf16* p) {
  return *reinterpret_cast<const bf16x8*>(p);
}
__device__ __forceinline__ f16x8 ldh(const _Float16* p) {
  return *reinterpret_cast<const f16x8*>(p);
}
__device__ __forceinline__ f32x4 mf(bf16x8 a, bf16x8 b, f32x4 c) {
  return __builtin_amdgcn_mfma_f32_16x16x32_bf16(a, b, c, 0, 0, 0);
}
__device__ __forceinline__ f32x4 mh(f16x8 a, f16x8 b, f32x4 c) {
  return __builtin_amdgcn_mfma_f32_16x16x32_f16(a, b, c, 0, 0, 0);
}
__device__ __forceinline__ void split2(float v, bf16& hi, bf16& lo) {
  hi = __float2bfloat16(v);
  lo = __float2bfloat16(v - __bfloat162float(hi));
}
__device__ __forceinline__ void split2h(float v, _Float16& hi, _Float16& lo) {
  hi = (_Float16)v;
  lo = (_Float16)(v - (float)hi);
}

// Per-phase cell table (single-layer dispatches), passed by value.
struct GruPhase {
  int ncells;
  int zmask;             // bit c: t==0 (skip gh GEMM, h_prev = 0)
  unsigned a1off[13];    // A1 element offset per cell
  unsigned hoff[13];     // h_prev element offset per cell
  unsigned ooff[13];     // h_out  element offset per cell
};

// Merged dual-layer cell table (<=25 cells: L0(s) + L1(s-1)), by value.
struct GruPhase2 {
  int ncells;
  unsigned zmask;        // bit c: t==0 cell
  unsigned laymask;      // bit c: cell is layer-1
  unsigned a1off[25];
  unsigned hoff[25];
  unsigned ooff[25];
};

// ---------------------------------------------------------------------------
// k_swzh: swizzle a row-major (Nsrc x Ksrc) fp32 weight into KT-MAJOR MFMA
// B-frag order as SINGLE fp16 (W precision 2^-11 rel; the 2-term fp16
// scheme keeps A at 2^-22 via hi/lo). Tile (kt,nt) at elem
// (kt*ntiles+nt)*512; lane l holds W[nt*16+(l&15)][kt*32+(l>>4)*8+j].
// ---------------------------------------------------------------------------
__global__ void k_swzh(const float* __restrict__ src, _Float16* __restrict__ dh,
                       int Nsrc, int Ksrc, int ntiles) {
  int idx = blockIdx.x * 256 + threadIdx.x;   // ((kt*ntiles+nt), lane)
  int l = idx & 63;
  int ktnt = idx >> 6;
  int nt = ktnt % ntiles, kt = ktnt / ntiles;
  int n = nt * 16 + (l & 15);
  int k0 = kt * 32 + (l >> 4) * 8;
#pragma unroll
  for (int j = 0; j < 8; ++j) {
    int k = k0 + j;
    float v = (n < Nsrc && k < Ksrc) ? src[(size_t)n * Ksrc + k] : 0.f;
    dh[(size_t)idx * 8 + j] = (_Float16)v;
  }
}

// k_swz2: bf16 hi/lo swizzle -- retained for W_out (out_m keeps 3-term bf16).
__global__ void k_swz2(const float* __restrict__ src, bf16* __restrict__ dhi,
                       bf16* __restrict__ dlo, int Nsrc, int Ksrc, int ntiles) {
  int idx = blockIdx.x * 256 + threadIdx.x;
  int l = idx & 63;
  int ktnt = idx >> 6;
  int nt = ktnt % ntiles, kt = ktnt / ntiles;
  int n = nt * 16 + (l & 15);
  int k0 = kt * 32 + (l >> 4) * 8;
#pragma unroll
  for (int j = 0; j < 8; ++j) {
    int k = k0 + j;
    float v = (n < Nsrc && k < Ksrc) ? src[(size_t)n * Ksrc + k] : 0.f;
    bf16 h, lo;
    split2(v, h, lo);
    dhi[(size_t)idx * 8 + j] = h;
    dlo[(size_t)idx * 8 + j] = lo;
  }
}

// Setup: 26-slot hi/lo fp16 token buffers, fp32 residual from x[:,12,:].
__global__ void k_setup(const float* __restrict__ x, _Float16* __restrict__ th,
                        _Float16* __restrict__ tl, float* __restrict__ res) {
  int idx = blockIdx.x * 256 + threadIdx.x;
  const int total = 26 * BB * YP;
  if (idx < total) {
    int k = idx % YP;
    int b = (idx / YP) % BB;
    int s = idx / (YP * BB);
    float v = 0.f;
    if (s < TT && k < YY) v = x[((size_t)b * TT + s) * YY + k];
    _Float16 h, lo;
    split2h(v, h, lo);
    th[idx] = h; tl[idx] = lo;
  }
  if (idx < BB * YY) {
    int yy = idx % YY;
    int b = idx / YY;
    res[idx] = x[((size_t)b * TT + 12) * YY + yy];
  }
}

// ===========================================================================
// GRU_BODY (fp16 2-term, BK=64): process kts in PAIRS per pipeline phase --
// stage both kts' W (24 tiles, 24 KiB), prefetch both kts' A-frags, run
// 2x12-tile MFMA between barriers. Barriers per L1 cell 40 -> 21 (the
// full-drain __syncthreads stall was ~25-30% of cycles at BK=32).
// Per-accumulator MFMA order unchanged (kt then kt+1) -> bitwise-identical.
// Requires KT1r even (6 or 16). LDS = 2 x 24 KiB = 48 KiB -> 2 blocks/CU.
// ===========================================================================
#define GRU_BODY()                                                            \
  const int KT2 = zero_h ? 0 : 16;                                            \
  const f32x4 vzero = {0.f, 0.f, 0.f, 0.f};                                   \
  f32x4 arz[2][2][4];                                                         \
  f32x4 axn[2][4], ahn[2][4];                                                 \
  _Pragma("unroll")                                                           \
  for (int rf = 0; rf < 2; ++rf)                                              \
    _Pragma("unroll")                                                         \
    for (int ntl = 0; ntl < 4; ++ntl) {                                       \
      arz[rf][0][ntl] = vzero; arz[rf][1][ntl] = vzero;                       \
      axn[rf][ntl] = vzero; ahn[rf][ntl] = vzero;                             \
    }                                                                         \
  /* staging: 24 tiles (kk*12 + g*4 + ntl) x 64 units; 6 units/thread */      \
  int tl2a[6];                                                                \
  size_t soff[6];                                                             \
  _Pragma("unroll")                                                           \
  for (int r = 0; r < 6; ++r) {                                               \
    const int tl2 = r * 4 + w;                                                \
    const int kk = tl2 / 12, rem = tl2 % 12;                                  \
    const int g = rem >> 2, ntl = rem & 3;                                    \
    const int ntg = g * 32 + (cw >> 4) + ntl;                                 \
    tl2a[r] = tl2;                                                            \
    soff[r] = ((size_t)(kk * NT + ntg) * 64 + l) * 8;                         \
  }                                                                           \
  auto stage_load2 = [&](const _Float16* W, int ktW, f16x8 (&v)[6]) {         \
    _Pragma("unroll")                                                         \
    for (int r = 0; r < 6; ++r)                                               \
      v[r] = ldh(W + soff[r] + (size_t)ktW * (NT * 512));                     \
  };                                                                          \
  auto stage_write2 = [&](f16x8 (&v)[6], int buf) {                           \
    _Pragma("unroll")                                                         \
    for (int r = 0; r < 6; ++r)                                               \
      *(f16x8*)(&Bl[buf][tl2a[r]][l * 8]) = v[r];                             \
  };                                                                          \
  auto aload2 = [&](const _Float16* Ah, const _Float16* Al, int lda, int ktA, \
                    f16x8 (&d)[2][2][2]) {                                    \
    _Pragma("unroll")                                                         \
    for (int kk = 0; kk < 2; ++kk)                                            \
      _Pragma("unroll")                                                       \
      for (int rf = 0; rf < 2; ++rf) {                                        \
        const size_t ao = (size_t)(m0 + rf * 16 + lr) * lda                   \
                          + (ktA + kk) * 32 + kq;                             \
        d[kk][rf][0] = ldh(Ah + ao);                                          \
        d[kk][rf][1] = ldh(Al + ao);                                          \
      }                                                                       \
  };                                                                          \
  auto compute2 = [&](f16x8 (&a)[2][2][2], int buf, f32x4 (&an)[2][4]) {      \
    _Pragma("unroll")                                                         \
    for (int kk = 0; kk < 2; ++kk)                                            \
      _Pragma("unroll")                                                       \
      for (int g = 0; g < 3; ++g)                                             \
        _Pragma("unroll")                                                     \
        for (int ntl = 0; ntl < 4; ++ntl) {                                   \
          f16x8 wv = *(const f16x8*)(&Bl[buf][kk * 12 + g * 4 + ntl][l * 8]); \
          _Pragma("unroll")                                                   \
          for (int rf = 0; rf < 2; ++rf) {                                    \
            if (g < 2)                                                        \
              arz[rf][g][ntl] = mh(a[kk][rf][1], wv,                          \
                                   mh(a[kk][rf][0], wv, arz[rf][g][ntl]));    \
            else                                                              \
              an[rf][ntl] = mh(a[kk][rf][1], wv,                              \
                               mh(a[kk][rf][0], wv, an[rf][ntl]));            \
          }                                                                   \
        }                                                                     \
  };                                                                          \
  auto acopy2 = [&](f16x8 (&dst)[2][2][2], f16x8 (&src)[2][2][2]) {           \
    _Pragma("unroll")                                                         \
    for (int kk = 0; kk < 2; ++kk)                                            \
      _Pragma("unroll")                                                       \
      for (int rf = 0; rf < 2; ++rf) {                                        \
        dst[kk][rf][0] = src[kk][rf][0];                                      \
        dst[kk][rf][1] = src[kk][rf][1];                                      \
      }                                                                       \
  };                                                                          \
  f16x8 w0[6], w1[6], aA[2][2][2], aB[2][2][2];                               \
  stage_load2(W1p, 0, w0);                                                    \
  aload2(A1h, A1l, lda1r, 0, aA);                                             \
  stage_write2(w0, 0);                                                        \
  __syncthreads();                                                            \
  for (int kt = 0; kt < KT1r; kt += 2) {                                      \
    const int buf = (kt >> 1) & 1;                                            \
    const bool more1 = (kt + 2 < KT1r);                                       \
    const bool next = more1 || (KT2 > 0);                                     \
    if (more1)      { stage_load2(W1p, kt + 2, w1); aload2(A1h, A1l, lda1r, kt + 2, aB); } \
    else if (KT2)   { stage_load2(W2p, 0, w1);      aload2(HPh, HPl, HH, 0, aB); }         \
    compute2(aA, buf, axn);                                                   \
    if (next) stage_write2(w1, buf ^ 1);                                      \
    __syncthreads();                                                          \
    if (next) acopy2(aA, aB);                                                 \
  }                                                                           \
  if (KT2) {                                                                  \
    const int pbase = KT1r >> 1;                                              \
    for (int kt = 0; kt < 16; kt += 2) {                                      \
      const int buf = (pbase + (kt >> 1)) & 1;                                \
      const bool next = (kt + 2 < 16);                                        \
      if (next) { stage_load2(W2p, kt + 2, w1); aload2(HPh, HPl, HH, kt + 2, aB); } \
      compute2(aA, buf, ahn);                                                 \
      if (next) stage_write2(w1, buf ^ 1);                                    \
      __syncthreads();                                                        \
      if (next) acopy2(aA, aB);                                               \
    }                                                                         \
  }                                                                           \
  _Pragma("unroll")                                                           \
  for (int ntl = 0; ntl < 4; ++ntl) {                                         \
    const int col = cw + ntl * 16 + lr;                                       \
    const float bx0 = b1p[col], bx1 = b1p[col + HH], bx2 = b1p[col + 2 * HH]; \
    const float bh0 = b2p[col], bh1 = b2p[col + HH], bh2 = b2p[col + 2 * HH]; \
    _Pragma("unroll")                                                         \
    for (int rf = 0; rf < 2; ++rf)                                            \
      _Pragma("unroll")                                                       \
      for (int i = 0; i < 4; ++i) {                                           \
        const int row = m0 + rf * 16 + lq * 4 + i;                            \
        const float rr = sigf(arz[rf][0][ntl][i] + bx0 + bh0);                \
        const float zz = sigf(arz[rf][1][ntl][i] + bx1 + bh1);                \
        const float nn = tanhf(axn[rf][ntl][i] + bx2 + rr * (ahn[rf][ntl][i] + bh2)); \
        float hp = 0.f;                                                       \
        const size_t hidx = (size_t)row * HH + col;                           \
        if (!zero_h)                                                          \
          hp = (float)HPh[hidx] + (float)HPl[hidx];                           \
        const float hn = (1.f - zz) * nn + zz * hp;                           \
        _Float16 sh, sl;                                                      \
        split2h(hn, sh, sl);                                                  \
        HOh[hidx] = sh;                                                       \
        HOl[hidx] = sl;                                                       \
      }                                                                       \
  }

// ---------------------------------------------------------------------------
// gru2: single-layer kernel (128x64 tile, validated R6 grid orientation:
// x=colgroup -> XCD-local W; occ=2 validated R13). fp16 2-term, BK=64.
// ---------------------------------------------------------------------------
template <int KT1>
__global__ __launch_bounds__(256, 2) void gru2(
    const _Float16* __restrict__ a1h, const _Float16* __restrict__ a1l, int lda1,
    const _Float16* __restrict__ W1, const float* __restrict__ b1,
    const _Float16* __restrict__ hbh, const _Float16* __restrict__ hbl,
    const _Float16* __restrict__ W2, const float* __restrict__ b2,
    _Float16* __restrict__ obh, _Float16* __restrict__ obl,
    GruPhase ph)
{
  __shared__ __align__(16) _Float16 Bl[2][24][512];
  const int tid = threadIdx.x;
  const int w = tid >> 6, l = tid & 63;
  const int lr = l & 15, lq = l >> 4, kq = lq * 8;
  const int cell = blockIdx.y >> 3, rt = blockIdx.y & 7;
  const int cw = blockIdx.x * 64;
  const int m0 = rt * 128 + w * 32;
  const _Float16* A1h = a1h + ph.a1off[cell];
  const _Float16* A1l = a1l + ph.a1off[cell];
  const _Float16* HPh = hbh + ph.hoff[cell];
  const _Float16* HPl = hbl + ph.hoff[cell];
  _Float16* HOh = obh + ph.ooff[cell];
  _Float16* HOl = obl + ph.ooff[cell];
  const int zero_h = (ph.zmask >> cell) & 1;
  const int KT1r = KT1;
  const int lda1r = lda1;
  const _Float16 *W1p = W1, *W2p = W2;
  const float *b1p = b1, *b2p = b2;
  GRU_BODY()
}

// ---------------------------------------------------------------------------
// gru2m: MERGED dual-layer dispatch, D(s) = L0(s) u L1(s-1) (R10/R11
// verified legal for all s<=12 via parity double-buffer). fp16 2-term, BK=64.
// ---------------------------------------------------------------------------
__global__ __launch_bounds__(256, 2) void gru2m(
    const _Float16* __restrict__ tokh, const _Float16* __restrict__ tokl,
    _Float16* __restrict__ h0h, _Float16* __restrict__ h0l,
    _Float16* __restrict__ h1h, _Float16* __restrict__ h1l,
    const _Float16* __restrict__ W0, const _Float16* __restrict__ Wh0,
    const float* __restrict__ bi0, const float* __restrict__ bh0,
    const _Float16* __restrict__ Wi1, const _Float16* __restrict__ Wh1,
    const float* __restrict__ bi1, const float* __restrict__ bh1,
    GruPhase2 ph)
{
  __shared__ __align__(16) _Float16 Bl[2][24][512];
  const int tid = threadIdx.x;
  const int w = tid >> 6, l = tid & 63;
  const int lr = l & 15, lq = l >> 4, kq = lq * 8;
  const int cell = blockIdx.y >> 3, rt = blockIdx.y & 7;
  const int cw = blockIdx.x * 64;
  const int m0 = rt * 128 + w * 32;
  const int isL1 = (ph.laymask >> cell) & 1;
  const int KT1r = isL1 ? (HH / 32) : (YP / 32);
  const int lda1r = isL1 ? HH : YP;
  const _Float16* A1h = (isL1 ? h0h : tokh) + ph.a1off[cell];
  const _Float16* A1l = (isL1 ? h0l : tokl) + ph.a1off[cell];
  const _Float16* HPh = (isL1 ? h1h : h0h) + ph.hoff[cell];
  const _Float16* HPl = (isL1 ? h1l : h0l) + ph.hoff[cell];
  _Float16* HOh = (isL1 ? h1h : h0h) + ph.ooff[cell];
  _Float16* HOl = (isL1 ? h1l : h0l) + ph.ooff[cell];
  const _Float16* W1p = isL1 ? Wi1 : W0;
  const _Float16* W2p = isL1 ? Wh1 : Wh0;
  const float* b1p = isL1 ? bi1 : bi0;
  const float* b2p = isL1 ? bh1 : bh0;
  const int zero_h = (ph.zmask >> cell) & 1;
  GRU_BODY()
}

// ---------------------------------------------------------------------------
// gru2n (small-C path): 128x32 tile, fp16 2-term, BK=64 (12 tiles/pair,
// uniform 3 units/thread staging -- simpler than the BK=32 384-unit split).
// Halved barrier count directly shortens the latency chain in the decode
// tail (these dispatches are latency-bound, not work-bound). LDS 24 KiB.
// ---------------------------------------------------------------------------
template <int KT1>
__global__ __launch_bounds__(256) void gru2n(
    const _Float16* __restrict__ a1h, const _Float16* __restrict__ a1l, int lda1,
    const _Float16* __restrict__ W1, const float* __restrict__ b1,
    const _Float16* __restrict__ hbh, const _Float16* __restrict__ hbl,
    const _Float16* __restrict__ W2, const float* __restrict__ b2,
    _Float16* __restrict__ obh, _Float16* __restrict__ obl,
    GruPhase ph)
{
  __shared__ __align__(16) _Float16 Bl[2][12][512];
  const int tid = threadIdx.x;
  const int w = tid >> 6, l = tid & 63;
  const int lr = l & 15, lq = l >> 4, kq = lq * 8;
  const int cell = blockIdx.y >> 3, rt = blockIdx.y & 7;
  const int cw = blockIdx.x * 32;
  const int m0 = rt * 128 + w * 32;
  const _Float16* A1h = a1h + ph.a1off[cell];
  const _Float16* A1l = a1l + ph.a1off[cell];
  const _Float16* HPh = hbh + ph.hoff[cell];
  const _Float16* HPl = hbl + ph.hoff[cell];
  _Float16* HOh = obh + ph.ooff[cell];
  _Float16* HOl = obl + ph.ooff[cell];
  const int zero_h = (ph.zmask >> cell) & 1;
  const int KT2 = zero_h ? 0 : 16;

  const f32x4 vzero = {0.f, 0.f, 0.f, 0.f};
  f32x4 arz[2][2][2];
  f32x4 axn[2][2], ahn[2][2];
#pragma unroll
  for (int rf = 0; rf < 2; ++rf)
#pragma unroll
    for (int ntl = 0; ntl < 2; ++ntl) {
      arz[rf][0][ntl] = vzero; arz[rf][1][ntl] = vzero;
      axn[rf][ntl] = vzero; ahn[rf][ntl] = vzero;
    }

  // staging: 12 tiles (kk*6 + g*2 + ntl) x 64 units; 3 units/thread
  int tl2a[3];
  size_t soff[3];
#pragma unroll
  for (int r = 0; r < 3; ++r) {
    const int tl2 = r * 4 + w;
    const int kk = tl2 / 6, rem = tl2 % 6;
    const int g = rem >> 1, ntl = rem & 1;
    const int ntg = g * 32 + (cw >> 4) + ntl;
    tl2a[r] = tl2;
    soff[r] = ((size_t)(kk * NT + ntg) * 64 + l) * 8;
  }

  auto stage_load2 = [&](const _Float16* W, int ktW, f16x8 (&v)[3]) {
#pragma unroll
    for (int r = 0; r < 3; ++r)
      v[r] = ldh(W + soff[r] + (size_t)ktW * (NT * 512));
  };
  auto stage_write2 = [&](f16x8 (&v)[3], int buf) {
#pragma unroll
    for (int r = 0; r < 3; ++r)
      *(f16x8*)(&Bl[buf][tl2a[r]][l * 8]) = v[r];
  };
  auto aload2 = [&](const _Float16* Ah, const _Float16* Al, int lda, int ktA,
                    f16x8 (&d)[2][2][2]) {
#pragma unroll
    for (int kk = 0; kk < 2; ++kk)
#pragma unroll
      for (int rf = 0; rf < 2; ++rf) {
        const size_t ao = (size_t)(m0 + rf * 16 + lr) * lda
                          + (ktA + kk) * 32 + kq;
        d[kk][rf][0] = ldh(Ah + ao);
        d[kk][rf][1] = ldh(Al + ao);
      }
  };
  auto compute2 = [&](f16x8 (&a)[2][2][2], int buf, f32x4 (&an)[2][2]) {
#pragma unroll
    for (int kk = 0; kk < 2; ++kk)
#pragma unroll
      for (int g = 0; g < 3; ++g)
#pragma unroll
        for (int ntl = 0; ntl < 2; ++ntl) {
          f16x8 wv = *(const f16x8*)(&Bl[buf][kk * 6 + g * 2 + ntl][l * 8]);
#pragma unroll
          for (int rf = 0; rf < 2; ++rf) {
            if (g < 2)
              arz[rf][g][ntl] = mh(a[kk][rf][1], wv,
                                   mh(a[kk][rf][0], wv, arz[rf][g][ntl]));
            else
              an[rf][ntl] = mh(a[kk][rf][1], wv,
                               mh(a[kk][rf][0], wv, an[rf][ntl]));
          }
        }
  };
  auto acopy2 = [&](f16x8 (&dst)[2][2][2], f16x8 (&src)[2][2][2]) {
#pragma unroll
    for (int kk = 0; kk < 2; ++kk)
#pragma unroll
      for (int rf = 0; rf < 2; ++rf) {
        dst[kk][rf][0] = src[kk][rf][0];
        dst[kk][rf][1] = src[kk][rf][1];
      }
  };

  f16x8 w0[3], w1[3], aA[2][2][2], aB[2][2][2];

  stage_load2(W1, 0, w0);
  aload2(A1h, A1l, lda1, 0, aA);
  stage_write2(w0, 0);
  __syncthreads();

  for (int kt = 0; kt < KT1; kt += 2) {
    const int buf = (kt >> 1) & 1;
    const bool more1 = (kt + 2 < KT1);
    const bool next = more1 || (KT2 > 0);
    if (more1)      { stage_load2(W1, kt + 2, w1); aload2(A1h, A1l, lda1, kt + 2, aB); }
    else if (KT2)   { stage_load2(W2, 0, w1);      aload2(HPh, HPl, HH, 0, aB); }
    compute2(aA, buf, axn);
    if (next) stage_write2(w1, buf ^ 1);
    __syncthreads();
    if (next) acopy2(aA, aB);
  }
  if (KT2) {
    const int pbase = KT1 >> 1;
    for (int kt = 0; kt < 16; kt += 2) {
      const int buf = (pbase + (kt >> 1)) & 1;
      const bool next = (kt + 2 < 16);
      if (next) { stage_load2(W2, kt + 2, w1); aload2(HPh, HPl, HH, kt + 2, aB); }
      compute2(aA, buf, ahn);
      if (next) stage_write2(w1, buf ^ 1);
      __syncthreads();
      if (next) acopy2(aA, aB);
    }
  }

#pragma unroll
  for (int ntl = 0; ntl < 2; ++ntl) {
    const int col = cw + ntl * 16 + lr;
    const float bx0 = b1[col], bx1 = b1[col + HH], bx2 = b1[col + 2 * HH];
    const float bh0 = b2[col], bh1 = b2[col + HH], bh2 = b2[col + 2 * HH];
#pragma unroll
    for (int rf = 0; rf < 2; ++rf)
#pragma unroll
      for (int i = 0; i < 4; ++i) {
        const int row = m0 + rf * 16 + lq * 4 + i;
        const float rr = sigf(arz[rf][0][ntl][i] + bx0 + bh0);
        const float zz = sigf(arz[rf][1][ntl][i] + bx1 + bh1);
        const float nn = tanhf(axn[rf][ntl][i] + bx2 + rr * (ahn[rf][ntl][i] + bh2));
        float hp = 0.f;
        const size_t hidx = (size_t)row * HH + col;
        if (!zero_h)
          hp = (float)HPh[hidx] + (float)HPl[hidx];
        const float hn = (1.f - zz) * nn + zz * hp;
        _Float16 sh, sl;
        split2h(hn, sh, sl);
        HOh[hidx] = sh;
        HOl[hidx] = sl;
      }
  }
}

// ---------------------------------------------------------------------------
// Output projection (MFMA, bf16 3-term unchanged): o = relu(h1)@W_out^T
// + b_out + res. h1 inputs fp16 hi/lo. grid(6,8) = 48 blocks.
// ---------------------------------------------------------------------------
__global__ __launch_bounds__(256) void out_m(
    const _Float16* __restrict__ h1h, const _Float16* __restrict__ h1l,
    const bf16* __restrict__ Wh, const bf16* __restrict__ Wl,
    const float* __restrict__ bo,
    float* __restrict__ res,
    _Float16* __restrict__ yh, _Float16* __restrict__ yl,
    float* __restrict__ outp, int d)
{
  const int tid = threadIdx.x;
  const int w = tid >> 6, l = tid & 63;
  const int lr = l & 15, lq = l >> 4, kq = lq * 8;
  const int m0 = blockIdx.y * 128 + w * 32;
  const int cw = blockIdx.x * 32;

  const f32x4 vzero = {0.f, 0.f, 0.f, 0.f};
  f32x4 acc[2][2];
#pragma unroll
  for (int rf = 0; rf < 2; ++rf)
#pragma unroll
    for (int ntl = 0; ntl < 2; ++ntl) acc[rf][ntl] = vzero;

  for (int kt = 0; kt < HH / 32; ++kt) {
    bf16x8 ah[2], al[2];
#pragma unroll
    for (int rf = 0; rf < 2; ++rf) {
      const size_t ao = (size_t)(m0 + rf * 16 + lr) * HH + kt * 32 + kq;
      f16x8 hh = ldh(h1h + ao);
      f16x8 hl = ldh(h1l + ao);
#pragma unroll
      for (int j = 0; j < 8; ++j) {
        float v = fmaxf((float)hh[j] + (float)hl[j], 0.f);
        __bf16 vh = (__bf16)v;
        __bf16 vl = (__bf16)(v - (float)vh);
        ah[rf][j] = vh;
        al[rf][j] = vl;
      }
    }
#pragma unroll
    for (int ntl = 0; ntl < 2; ++ntl) {
      const int nt = (cw >> 4) + ntl;
      const size_t bo_ = ((size_t)(kt * NTO + nt) * 64 + l) * 8;
      bf16x8 bh = ldf(Wh + bo_);
      bf16x8 bl = ldf(Wl + bo_);
#pragma unroll
      for (int rf = 0; rf < 2; ++rf)
        acc[rf][ntl] = mf(ah[rf], bl, mf(al[rf], bh,
                          mf(ah[rf], bh, acc[rf][ntl])));
    }
  }

#pragma unroll
  for (int ntl = 0; ntl < 2; ++ntl) {
    const int col = cw + ntl * 16 + lr;
    if (col >= YY) continue;           // padded cols 188..191: no writes
    const float bc = bo[col];
#pragma unroll
    for (int rf = 0; rf < 2; ++rf)
#pragma unroll
      for (int i = 0; i < 4; ++i) {
        const int row = m0 + rf * 16 + lq * 4 + i;
        const int ridx = row * YY + col;
        float o = acc[rf][ntl][i] + bc + res[ridx];
        res[ridx] = o;
        outp[((size_t)row * DS + d) * YY + col] = o;
        _Float16 sh, sl;
        split2h(o, sh, sl);
        yh[(size_t)row * YP + col] = sh;
        yl[(size_t)row * YP + col] = sl;
      }
  }
}

extern "C" void kernel_launch(void* const* d_in, const int* in_sizes, int n_in,
                              void* d_out, int out_size, void* d_ws, size_t ws_size,
                              hipStream_t stream)
{
  // role mapping insurance (dict-order signature, greedy fallback)
  static const int sig_dict[11] = {2501632, 288768, 786432, 1536, 1536,
                                   786432, 786432, 1536, 1536, 96256, 188};
  int map[11];
  bool dict_ok = (n_in == 11);
  if (dict_ok)
    for (int r = 0; r < 11; ++r)
      if (in_sizes[r] != sig_dict[r]) { dict_ok = false; break; }
  if (dict_ok) { for (int r = 0; r < 11; ++r) map[r] = r; }
  else {
    bool used[16] = {};
    for (int r = 0; r < 11; ++r) {
      map[r] = r < n_in ? r : 0;
      for (int i = 0; i < n_in && i < 16; ++i)
        if (!used[i] && in_sizes[i] == sig_dict[r]) { map[r] = i; used[i] = true; break; }
    }
  }
  const float* x     = (const float*)d_in[map[0]];
  const float* W_ih0 = (const float*)d_in[map[1]];
  const float* W_hh0 = (const float*)d_in[map[2]];
  const float* b_ih0 = (const float*)d_in[map[3]];
  const float* b_hh0 = (const float*)d_in[map[4]];
  const float* W_ih1 = (const float*)d_in[map[5]];
  const float* W_hh1 = (const float*)d_in[map[6]];
  const float* b_ih1 = (const float*)d_in[map[7]];
  const float* b_hh1 = (const float*)d_in[map[8]];
  const float* W_out = (const float*)d_in[map[9]];
  const float* b_out = (const float*)d_in[map[10]];
  float* outp = (float*)d_out;

  const int S    = (ws_size >= (size_t)160 << 20) ? 13 : 7;
  const int SKEW = (S == 13) ? 1 : 2;
  const int NPH  = 12 * SKEW + 13;

  char* p = (char*)d_ws;
  auto alloc = [&](size_t bytes) { char* q = p; p += (bytes + 255) & ~(size_t)255; return q; };
  _Float16* tokh = (_Float16*)alloc((size_t)26 * BB * YP * 2);
  _Float16* tokl = (_Float16*)alloc((size_t)26 * BB * YP * 2);
  _Float16* W0  = (_Float16*)alloc((size_t)GG * YP * 2);
  _Float16* Wh0 = (_Float16*)alloc((size_t)GG * HH * 2);
  _Float16* Wi1 = (_Float16*)alloc((size_t)GG * HH * 2);
  _Float16* Wh1 = (_Float16*)alloc((size_t)GG * HH * 2);
  bf16* Woh  = (bf16*)alloc((size_t)YP * HH * 2);   // W_out frags (bf16 hi/lo)
  bf16* Wol  = (bf16*)alloc((size_t)YP * HH * 2);
  _Float16* h0h = (_Float16*)alloc((size_t)2 * S * BB * HH * 2);  // parity x slot
  _Float16* h0l = (_Float16*)alloc((size_t)2 * S * BB * HH * 2);
  _Float16* h1h = (_Float16*)alloc((size_t)2 * S * BB * HH * 2);
  _Float16* h1l = (_Float16*)alloc((size_t)2 * S * BB * HH * 2);
  float* res = (float*)alloc((size_t)BB * YY * 4);

  k_setup<<<(26 * BB * YP + 255) / 256, 256, 0, stream>>>(x, tokh, tokl, res);
  k_swzh<<<NT * (YP / 32) * 64 / 256, 256, 0, stream>>>(W_ih0, W0, GG, YY, NT);
  k_swzh<<<NT * (HH / 32) * 64 / 256, 256, 0, stream>>>(W_hh0, Wh0, GG, HH, NT);
  k_swzh<<<NT * (HH / 32) * 64 / 256, 256, 0, stream>>>(W_ih1, Wi1, GG, HH, NT);
  k_swzh<<<NT * (HH / 32) * 64 / 256, 256, 0, stream>>>(W_hh1, Wh1, GG, HH, NT);
  k_swz2<<<NTO * (HH / 32) * 64 / 256, 256, 0, stream>>>(W_out, Woh, Wol, YY, HH, NTO);

  // phase cell-table builder (single-layer structs, SKEW-general)
  auto buildPhase = [&](int phs, GruPhase& P0, GruPhase& P1) {
    P0 = GruPhase{}; P1 = GruPhase{};
    const int pprev = (phs + 1) & 1, pcur = phs & 1;
    int C = 0;
    for (int d = 0; d < DS; ++d) {
      int t = phs - SKEW * d;
      if (t < 0 || t > 12) continue;
      int c = C++;
      P0.a1off[c] = (unsigned)((d + t) * BB * YP);
      P0.hoff[c]  = (unsigned)((pprev * S + d % S) * BB * HH);
      P0.ooff[c]  = (unsigned)((pcur * S + d % S) * BB * HH);
      if (t == 0) P0.zmask |= 1 << c;
      P1.a1off[c] = P0.ooff[c];
      P1.hoff[c]  = P0.hoff[c];
      P1.ooff[c]  = P0.ooff[c];
    }
    P0.ncells = P1.ncells = C;
    P1.zmask = P0.zmask;
    return C;
  };
  auto launchL0 = [&](const GruPhase& P0, int C) {
    if (C <= 5) {
      gru2n<YP / 32><<<dim3(16, C * 8), 256, 0, stream>>>(
          tokh, tokl, YP, W0, b_ih0, h0h, h0l, Wh0, b_hh0, h0h, h0l, P0);
    } else {
      gru2<YP / 32><<<dim3(8, C * 8), 256, 0, stream>>>(
          tokh, tokl, YP, W0, b_ih0, h0h, h0l, Wh0, b_hh0, h0h, h0l, P0);
    }
  };
  auto launchL1 = [&](const GruPhase& P1, int C) {
    if (C <= 5) {
      gru2n<HH / 32><<<dim3(16, C * 8), 256, 0, stream>>>(
          h0h, h0l, HH, Wi1, b_ih1, h1h, h1l, Wh1, b_hh1, h1h, h1l, P1);
    } else {
      gru2<HH / 32><<<dim3(8, C * 8), 256, 0, stream>>>(
          h0h, h0l, HH, Wi1, b_ih1, h1h, h1l, Wh1, b_hh1, h1h, h1l, P1);
    }
  };
  auto launchOut = [&](int d) {
    const int pph = 12 + SKEW * d;
    const size_t hoff = (size_t)((pph & 1) * S + d % S) * BB * HH;
    out_m<<<dim3(6, 8), 256, 0, stream>>>(
        h1h + hoff, h1l + hoff, Woh, Wol, b_out, res,
        tokh + (size_t)(13 + d) * BB * YP, tokl + (size_t)(13 + d) * BB * YP,
        outp, d);
  };

  if (SKEW == 1) {
    // ---- merged wavefront D(s) = L0(s) + L1(s-1), s=0..12
    for (int s = 0; s <= 12; ++s) {
      GruPhase2 M{};
      int c = 0;
      {  // L0 cells of phase s
        const int pprev = (s + 1) & 1, pcur = s & 1;
        for (int d = 0; d < DS; ++d) {
          int t = s - d;
          if (t < 0 || t > 12) continue;
          M.a1off[c] = (unsigned)((d + t) * BB * YP);
          M.hoff[c]  = (unsigned)((pprev * S + d % S) * BB * HH);
          M.ooff[c]  = (unsigned)((pcur * S + d % S) * BB * HH);
          if (t == 0) M.zmask |= 1u << c;
          ++c;
        }
      }
      {  // L1 cells of phase s-1 (empty at s=0)
        const int pp = s - 1;
        const int pprev = (pp + 1) & 1, pcur = pp & 1;
        for (int d = 0; d < DS; ++d) {
          int t = pp - d;
          if (t < 0 || t > 12) continue;
          M.laymask |= 1u << c;
          M.a1off[c] = (unsigned)((pcur * S + d % S) * BB * HH);  // L0(pp) out
          M.hoff[c]  = (unsigned)((pprev * S + d % S) * BB * HH);
          M.ooff[c]  = (unsigned)((pcur * S + d % S) * BB * HH);
          if (t == 0) M.zmask |= 1u << c;
          ++c;
        }
      }
      M.ncells = c;
      gru2m<<<dim3(8, c * 8), 256, 0, stream>>>(
          tokh, tokl, h0h, h0l, h1h, h1l,
          W0, Wh0, b_ih0, b_hh0, Wi1, Wh1, b_ih1, b_hh1, M);
    }
    // ---- L1(12) standalone (C=13)
    {
      GruPhase P0, P1;
      int C = buildPhase(12, P0, P1);
      launchL1(P1, C);
    }
    // ---- decode: serial chain out_m(d) -> L0(13+d) -> L1(13+d)
    for (int d = 0; d <= 12; ++d) {
      launchOut(d);
      if (d < 12) {
        GruPhase P0, P1;
        int C = buildPhase(13 + d, P0, P1);
        launchL0(P0, C);
        launchL1(P1, C);
      }
    }
  } else {
    // SKEW=2 fallback: proven R6-style schedule (no merge)
    for (int phs = 0; phs < NPH; ++phs) {
      GruPhase P0, P1;
      int C = buildPhase(phs, P0, P1);
      launchL0(P0, C);
      launchL1(P1, C);
      if (phs >= 12 && (phs - 12) % SKEW == 0) launchOut((phs - 12) / SKEW);
    }
  }
}